// Round 1
// baseline (2981.532 us; speedup 1.0000x reference)
//
#include <hip/hip_runtime.h>
#include <stdint.h>

#define NN 100000
#define FIN 256
#define FHID 128
#define BN_EPS 1e-3f

// ---------------- degree accumulation ----------------
__global__ __launch_bounds__(256) void k_deg(const int* __restrict__ ei,
                                             const float* __restrict__ ew,
                                             float* __restrict__ deg, int E) {
    int e = blockIdx.x * blockDim.x + threadIdx.x;
    if (e < E) {
        int dst = ei[E + e];
        atomicAdd(&deg[dst], ew[e]);
    }
}

__global__ __launch_bounds__(256) void k_dinv(float* dd, int n) {
    int i = blockIdx.x * blockDim.x + threadIdx.x;
    if (i < n) {
        float d = dd[i] + 1.0f;   // +1 self loop; always > 0
        dd[i] = rsqrtf(d);
    }
}

// ---------------- fp32 GEMM: C[n,128] = X[n,K] * W[K,128] ----------------
template <int K>
__global__ __launch_bounds__(256) void k_gemm(const float* __restrict__ X,
                                              const float* __restrict__ W,
                                              float* __restrict__ C, int nrows) {
    __shared__ float Xs[64][68];     // +4 pad: 16B-aligned rows, few conflicts
    __shared__ float Ws[64][128];
    const int t = threadIdx.x;
    const int r0 = blockIdx.x * 64;
    const int c8 = (t & 15) * 8;
    const int r4 = (t >> 4) * 4;
    float acc[4][8];
#pragma unroll
    for (int i = 0; i < 4; i++)
#pragma unroll
        for (int j = 0; j < 8; j++) acc[i][j] = 0.f;

    for (int kt = 0; kt < K; kt += 64) {
        __syncthreads();
        // stage X tile (64 rows x 64 k) transpose-free
#pragma unroll
        for (int p = 0; p < 4; p++) {
            int row = p * 16 + (t >> 4);
            int kk = (t & 15) * 4;
            int gr = r0 + row;
            if (gr >= nrows) gr = nrows - 1;
            const float4 v = *reinterpret_cast<const float4*>(X + (size_t)gr * K + kt + kk);
            *reinterpret_cast<float4*>(&Xs[row][kk]) = v;
        }
        // stage W tile (64 k x 128 cols)
#pragma unroll
        for (int p = 0; p < 8; p++) {
            int idx = p * 256 + t;
            int k = idx >> 5;
            int c4 = (idx & 31) * 4;
            *reinterpret_cast<float4*>(&Ws[k][c4]) =
                *reinterpret_cast<const float4*>(W + (size_t)(kt + k) * 128 + c4);
        }
        __syncthreads();
#pragma unroll
        for (int k = 0; k < 64; k++) {
            const float4 w0 = *reinterpret_cast<const float4*>(&Ws[k][c8]);
            const float4 w1 = *reinterpret_cast<const float4*>(&Ws[k][c8 + 4]);
#pragma unroll
            for (int i = 0; i < 4; i++) {
                float xv = Xs[r4 + i][k];
                acc[i][0] += xv * w0.x; acc[i][1] += xv * w0.y;
                acc[i][2] += xv * w0.z; acc[i][3] += xv * w0.w;
                acc[i][4] += xv * w1.x; acc[i][5] += xv * w1.y;
                acc[i][6] += xv * w1.z; acc[i][7] += xv * w1.w;
            }
        }
    }
#pragma unroll
    for (int i = 0; i < 4; i++) {
        int gr = r0 + r4 + i;
        if (gr < nrows) {
            *reinterpret_cast<float4*>(C + (size_t)gr * 128 + c8) =
                make_float4(acc[i][0], acc[i][1], acc[i][2], acc[i][3]);
            *reinterpret_cast<float4*>(C + (size_t)gr * 128 + c8 + 4) =
                make_float4(acc[i][4], acc[i][5], acc[i][6], acc[i][7]);
        }
    }
}

// ---------------- agg init: agg = dinv^2 * h + b ----------------
__global__ __launch_bounds__(256) void k_init_agg(const float* __restrict__ h,
                                                  const float* __restrict__ dinv,
                                                  const float* __restrict__ b,
                                                  float* __restrict__ agg, int n) {
    int idx = blockIdx.x * blockDim.x + threadIdx.x;
    const int total = n * 32;  // float4 groups
    for (; idx < total; idx += gridDim.x * blockDim.x) {
        int node = idx >> 5;
        int c4 = (idx & 31) * 4;
        float di = dinv[node];
        float s = di * di;
        const float4 hv = *reinterpret_cast<const float4*>(h + (size_t)node * 128 + c4);
        const float4 bv = *reinterpret_cast<const float4*>(b + c4);
        *reinterpret_cast<float4*>(agg + (size_t)node * 128 + c4) =
            make_float4(hv.x * s + bv.x, hv.y * s + bv.y, hv.z * s + bv.z, hv.w * s + bv.w);
    }
}

// ---------------- edge scatter: agg[dst] += h[src] * norm ----------------
__global__ __launch_bounds__(256) void k_scatter(const float* __restrict__ h,
                                                 float* __restrict__ agg,
                                                 const int* __restrict__ ei,
                                                 const float* __restrict__ ew,
                                                 const float* __restrict__ dinv,
                                                 int E, int epw) {
    const int wave = (int)((blockIdx.x * (size_t)blockDim.x + threadIdx.x) >> 6);
    const int lane = threadIdx.x & 63;
    const long long base = (long long)wave * epw;
    for (int i = 0; i < epw; i++) {
        long long e = base + i;
        if (e >= E) return;
        int src = ei[e];
        int dst = ei[E + e];
        float norm = dinv[src] * ew[e] * dinv[dst];
        const float2 v = *reinterpret_cast<const float2*>(h + (size_t)src * 128 + lane * 2);
        float* out = agg + (size_t)dst * 128 + lane * 2;
        atomicAdd(out, v.x * norm);
        atomicAdd(out + 1, v.y * norm);
    }
}

// ---------------- per-feature sum / sumsq ----------------
__global__ __launch_bounds__(256) void k_stats(const float* __restrict__ x,
                                               float* __restrict__ stats, int n) {
    __shared__ float sdata[512];
    const int t = threadIdx.x;
    const int f = t & 127;
    float ls = 0.f, lsq = 0.f;
    for (int node = blockIdx.x * 2 + (t >> 7); node < n; node += gridDim.x * 2) {
        float v = x[(size_t)node * 128 + f];
        ls += v;
        lsq += v * v;
    }
    sdata[t] = ls;
    sdata[256 + t] = lsq;
    __syncthreads();
    if (t < 128) {
        atomicAdd(&stats[f], sdata[t] + sdata[t + 128]);
        atomicAdd(&stats[128 + f], sdata[256 + t] + sdata[256 + t + 128]);
    }
}

// ---------------- BN params: scale/shift per feature ----------------
__global__ void k_bn_params(const float* __restrict__ stats,
                            const float* __restrict__ g,
                            const float* __restrict__ beta,
                            float* __restrict__ prm, int n) {
    int f = threadIdx.x;  // 128 threads
    float inv_n = 1.0f / (float)n;
    float mu = stats[f] * inv_n;
    float var = stats[128 + f] * inv_n - mu * mu;
    float sc = rsqrtf(var + BN_EPS) * g[f];
    prm[f] = sc;
    prm[128 + f] = beta[f] - mu * sc;
}

// ---------------- BN apply + ReLU ----------------
__global__ __launch_bounds__(256) void k_bn_relu(const float* __restrict__ x,
                                                 float* __restrict__ y,
                                                 const float* __restrict__ prm, int n) {
    int idx = blockIdx.x * blockDim.x + threadIdx.x;
    const int total = n * 32;
    for (; idx < total; idx += gridDim.x * blockDim.x) {
        int node = idx >> 5;
        int c4 = (idx & 31) * 4;
        const float4 xv = *reinterpret_cast<const float4*>(x + (size_t)node * 128 + c4);
        const float4 sc = *reinterpret_cast<const float4*>(prm + c4);
        const float4 sh = *reinterpret_cast<const float4*>(prm + 128 + c4);
        float4 o;
        o.x = fmaxf(xv.x * sc.x + sh.x, 0.f);
        o.y = fmaxf(xv.y * sc.y + sh.y, 0.f);
        o.z = fmaxf(xv.z * sc.z + sh.z, 0.f);
        o.w = fmaxf(xv.w * sc.w + sh.w, 0.f);
        *reinterpret_cast<float4*>(y + (size_t)node * 128 + c4) = o;
    }
}

extern "C" void kernel_launch(void* const* d_in, const int* in_sizes, int n_in,
                              void* d_out, int out_size, void* d_ws, size_t ws_size,
                              hipStream_t stream) {
    const float* x   = (const float*)d_in[0];
    const int*   ei  = (const int*)d_in[1];
    const float* ew  = (const float*)d_in[2];
    const float* W0  = (const float*)d_in[3];
    const float* b0  = (const float*)d_in[4];
    const float* g0  = (const float*)d_in[5];
    const float* be0 = (const float*)d_in[6];
    const float* W1  = (const float*)d_in[7];
    const float* b1  = (const float*)d_in[8];
    const float* g1  = (const float*)d_in[9];
    const float* be1 = (const float*)d_in[10];
    float* out = (float*)d_out;

    const int N = in_sizes[0] / FIN;       // 100000
    const int E = in_sizes[2];             // 1600000

    float* A     = (float*)d_ws;                    // [N,128]
    float* B     = A + (size_t)N * FHID;            // [N,128]
    float* dinv  = B + (size_t)N * FHID;            // [N]
    float* stats = dinv + N;                        // 256 (reused per layer)
    float* prm   = stats + 256;                     // 256

    // --- degree / dinv ---
    hipMemsetAsync(dinv, 0, (size_t)N * sizeof(float), stream);
    k_deg<<<(E + 255) / 256, 256, 0, stream>>>(ei, ew, dinv, E);
    k_dinv<<<(N + 255) / 256, 256, 0, stream>>>(dinv, N);

    const int gemm_blocks = (N + 63) / 64;
    const int epw = 8;
    const int scatter_blocks = ((E + epw - 1) / epw + 3) / 4;  // 4 waves/block

    // ================= layer 0 =================
    k_gemm<FIN><<<gemm_blocks, 256, 0, stream>>>(x, W0, A, N);
    k_init_agg<<<2048, 256, 0, stream>>>(A, dinv, b0, B, N);
    k_scatter<<<scatter_blocks, 256, 0, stream>>>(A, B, ei, ew, dinv, E, epw);
    hipMemsetAsync(stats, 0, 256 * sizeof(float), stream);
    k_stats<<<1024, 256, 0, stream>>>(B, stats, N);
    k_bn_params<<<1, 128, 0, stream>>>(stats, g0, be0, prm, N);
    k_bn_relu<<<2048, 256, 0, stream>>>(B, A, prm, N);   // y0 -> A

    // ================= layer 1 =================
    k_gemm<FHID><<<gemm_blocks, 256, 0, stream>>>(A, W1, B, N);
    k_init_agg<<<2048, 256, 0, stream>>>(B, dinv, b1, out, N);
    k_scatter<<<scatter_blocks, 256, 0, stream>>>(B, out, ei, ew, dinv, E, epw);
    hipMemsetAsync(stats, 0, 256 * sizeof(float), stream);
    k_stats<<<1024, 256, 0, stream>>>(out, stats, N);
    k_bn_params<<<1, 128, 0, stream>>>(stats, g1, be1, prm, N);
    k_bn_relu<<<2048, 256, 0, stream>>>(out, out, prm, N);
}

// Round 2
// 800.205 us; speedup vs baseline: 3.7260x; 3.7260x over previous
//
#include <hip/hip_runtime.h>
#include <stdint.h>

#define FIN 256
#define FHID 128
#define BN_EPS 1e-3f

// ---------------- degree (weighted) + count histogram ----------------
__global__ __launch_bounds__(256) void k_deg_hist(const int* __restrict__ ei,
                                                  const float* __restrict__ ew,
                                                  float* __restrict__ degw,
                                                  int* __restrict__ cnt, int E) {
    int e = blockIdx.x * blockDim.x + threadIdx.x;
    if (e < E) {
        int dst = ei[E + e];
        atomicAdd(&degw[dst], ew[e]);
        atomicAdd(&cnt[dst], 1);
    }
}

__global__ __launch_bounds__(256) void k_dinv(float* dd, int n) {
    int i = blockIdx.x * blockDim.x + threadIdx.x;
    if (i < n) {
        float d = dd[i] + 1.0f;   // +1 self loop; always > 0
        dd[i] = rsqrtf(d);
    }
}

// ---------------- exclusive scan (3-kernel) ----------------
__global__ __launch_bounds__(256) void k_scan_block(const int* __restrict__ cnt,
                                                    int* __restrict__ rowptr,
                                                    int* __restrict__ bsums, int n) {
    __shared__ int lds[256];
    const int base = blockIdx.x * 1024;
    const int t = threadIdx.x;
    int v[4];
    int s = 0;
#pragma unroll
    for (int i = 0; i < 4; i++) {
        int idx = base + t * 4 + i;
        v[i] = (idx < n) ? cnt[idx] : 0;
        s += v[i];
    }
    lds[t] = s;
    __syncthreads();
    for (int off = 1; off < 256; off <<= 1) {
        int add = (t >= off) ? lds[t - off] : 0;
        __syncthreads();
        lds[t] += add;
        __syncthreads();
    }
    int run = lds[t] - s;
#pragma unroll
    for (int i = 0; i < 4; i++) {
        int idx = base + t * 4 + i;
        if (idx < n) rowptr[idx] = run;
        run += v[i];
    }
    if (t == 255) bsums[blockIdx.x] = lds[255];
}

__global__ void k_scan_sums(int* bsums, int nb) {
    if (threadIdx.x == 0 && blockIdx.x == 0) {
        int run = 0;
        for (int i = 0; i < nb; i++) { int v = bsums[i]; bsums[i] = run; run += v; }
    }
}

__global__ __launch_bounds__(256) void k_scan_apply(int* __restrict__ rowptr,
                                                    const int* __restrict__ bsums,
                                                    int n, int E) {
    int idx = blockIdx.x * 256 + threadIdx.x;
    if (idx < n) rowptr[idx] += bsums[idx >> 10];
    if (idx == n) rowptr[n] = E;
}

// ---------------- CSR fill ----------------
__global__ __launch_bounds__(256) void k_fill(const int* __restrict__ ei,
                                              const float* __restrict__ ew,
                                              const float* __restrict__ dinv,
                                              const int* __restrict__ rowptr,
                                              int* __restrict__ cnt,
                                              int2* __restrict__ recs, int E) {
    int e = blockIdx.x * blockDim.x + threadIdx.x;
    if (e < E) {
        int src = ei[e];
        int dst = ei[E + e];
        int slot = atomicSub(&cnt[dst], 1) - 1;
        int pos = rowptr[dst] + slot;
        float norm = dinv[src] * ew[e] * dinv[dst];
        recs[pos] = make_int2(src, __float_as_int(norm));
    }
}

// ---------------- gather (fused self-loop + bias) ----------------
__global__ __launch_bounds__(256) void k_gather(const float* __restrict__ h,
                                                float* __restrict__ agg,
                                                const int* __restrict__ rowptr,
                                                const int2* __restrict__ recs,
                                                const float* __restrict__ dinv,
                                                const float* __restrict__ bias, int n) {
    const int node = (int)((blockIdx.x * (size_t)blockDim.x + threadIdx.x) >> 6);
    if (node >= n) return;
    const int lane = (threadIdx.x & 63) * 2;
    const float di = dinv[node];
    const float s = di * di;
    const float2 hv = *reinterpret_cast<const float2*>(h + (size_t)node * 128 + lane);
    const float2 bv = *reinterpret_cast<const float2*>(bias + lane);
    float ax = hv.x * s + bv.x;
    float ay = hv.y * s + bv.y;
    int e = rowptr[node];
    const int end = rowptr[node + 1];
    for (; e + 1 < end; e += 2) {
        const int2 r0 = recs[e];
        const int2 r1 = recs[e + 1];
        const float2 v0 = *reinterpret_cast<const float2*>(h + (size_t)r0.x * 128 + lane);
        const float2 v1 = *reinterpret_cast<const float2*>(h + (size_t)r1.x * 128 + lane);
        const float n0 = __int_as_float(r0.y);
        const float n1 = __int_as_float(r1.y);
        ax += v0.x * n0; ay += v0.y * n0;
        ax += v1.x * n1; ay += v1.y * n1;
    }
    if (e < end) {
        const int2 r0 = recs[e];
        const float2 v0 = *reinterpret_cast<const float2*>(h + (size_t)r0.x * 128 + lane);
        const float n0 = __int_as_float(r0.y);
        ax += v0.x * n0; ay += v0.y * n0;
    }
    *reinterpret_cast<float2*>(agg + (size_t)node * 128 + lane) = make_float2(ax, ay);
}

// ---------------- fallback atomic path ----------------
__global__ __launch_bounds__(256) void k_init_agg(const float* __restrict__ h,
                                                  const float* __restrict__ dinv,
                                                  const float* __restrict__ b,
                                                  float* __restrict__ agg, int n) {
    int idx = blockIdx.x * blockDim.x + threadIdx.x;
    const int total = n * 32;
    for (; idx < total; idx += gridDim.x * blockDim.x) {
        int node = idx >> 5;
        int c4 = (idx & 31) * 4;
        float di = dinv[node];
        float s = di * di;
        const float4 hv = *reinterpret_cast<const float4*>(h + (size_t)node * 128 + c4);
        const float4 bv = *reinterpret_cast<const float4*>(b + c4);
        *reinterpret_cast<float4*>(agg + (size_t)node * 128 + c4) =
            make_float4(hv.x * s + bv.x, hv.y * s + bv.y, hv.z * s + bv.z, hv.w * s + bv.w);
    }
}

__global__ __launch_bounds__(256) void k_scatter(const float* __restrict__ h,
                                                 float* __restrict__ agg,
                                                 const int* __restrict__ ei,
                                                 const float* __restrict__ ew,
                                                 const float* __restrict__ dinv,
                                                 int E, int epw) {
    const int wave = (int)((blockIdx.x * (size_t)blockDim.x + threadIdx.x) >> 6);
    const int lane = threadIdx.x & 63;
    const long long base = (long long)wave * epw;
    for (int i = 0; i < epw; i++) {
        long long e = base + i;
        if (e >= E) return;
        int src = ei[e];
        int dst = ei[E + e];
        float norm = dinv[src] * ew[e] * dinv[dst];
        const float2 v = *reinterpret_cast<const float2*>(h + (size_t)src * 128 + lane * 2);
        float* o = agg + (size_t)dst * 128 + lane * 2;
        atomicAdd(o, v.x * norm);
        atomicAdd(o + 1, v.y * norm);
    }
}

// ---------------- fp32 GEMM ----------------
template <int K>
__global__ __launch_bounds__(256) void k_gemm(const float* __restrict__ X,
                                              const float* __restrict__ W,
                                              float* __restrict__ C, int nrows) {
    __shared__ float Xs[64][68];
    __shared__ float Ws[64][128];
    const int t = threadIdx.x;
    const int r0 = blockIdx.x * 64;
    const int c8 = (t & 15) * 8;
    const int r4 = (t >> 4) * 4;
    float acc[4][8];
#pragma unroll
    for (int i = 0; i < 4; i++)
#pragma unroll
        for (int j = 0; j < 8; j++) acc[i][j] = 0.f;

    for (int kt = 0; kt < K; kt += 64) {
        __syncthreads();
#pragma unroll
        for (int p = 0; p < 4; p++) {
            int row = p * 16 + (t >> 4);
            int kk = (t & 15) * 4;
            int gr = r0 + row;
            if (gr >= nrows) gr = nrows - 1;
            const float4 v = *reinterpret_cast<const float4*>(X + (size_t)gr * K + kt + kk);
            *reinterpret_cast<float4*>(&Xs[row][kk]) = v;
        }
#pragma unroll
        for (int p = 0; p < 8; p++) {
            int idx = p * 256 + t;
            int k = idx >> 5;
            int c4 = (idx & 31) * 4;
            *reinterpret_cast<float4*>(&Ws[k][c4]) =
                *reinterpret_cast<const float4*>(W + (size_t)(kt + k) * 128 + c4);
        }
        __syncthreads();
#pragma unroll
        for (int k = 0; k < 64; k++) {
            const float4 w0 = *reinterpret_cast<const float4*>(&Ws[k][c8]);
            const float4 w1 = *reinterpret_cast<const float4*>(&Ws[k][c8 + 4]);
#pragma unroll
            for (int i = 0; i < 4; i++) {
                float xv = Xs[r4 + i][k];
                acc[i][0] += xv * w0.x; acc[i][1] += xv * w0.y;
                acc[i][2] += xv * w0.z; acc[i][3] += xv * w0.w;
                acc[i][4] += xv * w1.x; acc[i][5] += xv * w1.y;
                acc[i][6] += xv * w1.z; acc[i][7] += xv * w1.w;
            }
        }
    }
#pragma unroll
    for (int i = 0; i < 4; i++) {
        int gr = r0 + r4 + i;
        if (gr < nrows) {
            *reinterpret_cast<float4*>(C + (size_t)gr * 128 + c8) =
                make_float4(acc[i][0], acc[i][1], acc[i][2], acc[i][3]);
            *reinterpret_cast<float4*>(C + (size_t)gr * 128 + c8 + 4) =
                make_float4(acc[i][4], acc[i][5], acc[i][6], acc[i][7]);
        }
    }
}

// ---------------- per-feature sum / sumsq ----------------
__global__ __launch_bounds__(256) void k_stats(const float* __restrict__ x,
                                               float* __restrict__ stats, int n) {
    __shared__ float sdata[512];
    const int t = threadIdx.x;
    const int f = t & 127;
    float ls = 0.f, lsq = 0.f;
    for (int node = blockIdx.x * 2 + (t >> 7); node < n; node += gridDim.x * 2) {
        float v = x[(size_t)node * 128 + f];
        ls += v;
        lsq += v * v;
    }
    sdata[t] = ls;
    sdata[256 + t] = lsq;
    __syncthreads();
    if (t < 128) {
        atomicAdd(&stats[f], sdata[t] + sdata[t + 128]);
        atomicAdd(&stats[128 + f], sdata[256 + t] + sdata[256 + t + 128]);
    }
}

__global__ void k_bn_params(const float* __restrict__ stats,
                            const float* __restrict__ g,
                            const float* __restrict__ beta,
                            float* __restrict__ prm, int n) {
    int f = threadIdx.x;
    float inv_n = 1.0f / (float)n;
    float mu = stats[f] * inv_n;
    float var = stats[128 + f] * inv_n - mu * mu;
    float sc = rsqrtf(var + BN_EPS) * g[f];
    prm[f] = sc;
    prm[128 + f] = beta[f] - mu * sc;
}

__global__ __launch_bounds__(256) void k_bn_relu(const float* __restrict__ x,
                                                 float* __restrict__ y,
                                                 const float* __restrict__ prm, int n) {
    int idx = blockIdx.x * blockDim.x + threadIdx.x;
    const int total = n * 32;
    for (; idx < total; idx += gridDim.x * blockDim.x) {
        int node = idx >> 5;
        int c4 = (idx & 31) * 4;
        const float4 xv = *reinterpret_cast<const float4*>(x + (size_t)node * 128 + c4);
        const float4 sc = *reinterpret_cast<const float4*>(prm + c4);
        const float4 sh = *reinterpret_cast<const float4*>(prm + 128 + c4);
        float4 o;
        o.x = fmaxf(xv.x * sc.x + sh.x, 0.f);
        o.y = fmaxf(xv.y * sc.y + sh.y, 0.f);
        o.z = fmaxf(xv.z * sc.z + sh.z, 0.f);
        o.w = fmaxf(xv.w * sc.w + sh.w, 0.f);
        *reinterpret_cast<float4*>(y + (size_t)node * 128 + c4) = o;
    }
}

extern "C" void kernel_launch(void* const* d_in, const int* in_sizes, int n_in,
                              void* d_out, int out_size, void* d_ws, size_t ws_size,
                              hipStream_t stream) {
    const float* x   = (const float*)d_in[0];
    const int*   ei  = (const int*)d_in[1];
    const float* ew  = (const float*)d_in[2];
    const float* W0  = (const float*)d_in[3];
    const float* b0  = (const float*)d_in[4];
    const float* g0  = (const float*)d_in[5];
    const float* be0 = (const float*)d_in[6];
    const float* W1  = (const float*)d_in[7];
    const float* b1  = (const float*)d_in[8];
    const float* g1  = (const float*)d_in[9];
    const float* be1 = (const float*)d_in[10];
    float* out = (float*)d_out;

    const int N = in_sizes[0] / FIN;
    const int E = in_sizes[2];
    const int NB = (N + 1023) / 1024;

    float* A      = (float*)d_ws;
    float* B      = A + (size_t)N * FHID;
    int2*  recs   = (int2*)(B + (size_t)N * FHID);
    float* dinv   = (float*)(recs + E);
    int*   cnt    = (int*)(dinv + N);
    int*   rowptr = cnt + N;
    int*   bsums  = rowptr + N + 1;
    float* stats  = (float*)(bsums + 128);
    float* prm    = stats + 256;

    const size_t need = (size_t)((char*)(prm + 256) - (char*)d_ws);
    const bool use_csr = ws_size >= need;

    const int gemm_blocks = (N + 63) / 64;

    if (use_csr) {
        hipMemsetAsync(dinv, 0, (size_t)N * 2 * sizeof(float), stream);  // degw + cnt
        k_deg_hist<<<(E + 255) / 256, 256, 0, stream>>>(ei, ew, dinv, cnt, E);
        k_dinv<<<(N + 255) / 256, 256, 0, stream>>>(dinv, N);
        k_scan_block<<<NB, 256, 0, stream>>>(cnt, rowptr, bsums, N);
        k_scan_sums<<<1, 64, 0, stream>>>(bsums, NB);
        k_scan_apply<<<(N + 256) / 256, 256, 0, stream>>>(rowptr, bsums, N, E);
        k_fill<<<(E + 255) / 256, 256, 0, stream>>>(ei, ew, dinv, rowptr, cnt, recs, E);

        const int gather_blocks = (N + 3) / 4;

        k_gemm<FIN><<<gemm_blocks, 256, 0, stream>>>(x, W0, A, N);
        k_gather<<<gather_blocks, 256, 0, stream>>>(A, B, rowptr, recs, dinv, b0, N);
        hipMemsetAsync(stats, 0, 256 * sizeof(float), stream);
        k_stats<<<1024, 256, 0, stream>>>(B, stats, N);
        k_bn_params<<<1, 128, 0, stream>>>(stats, g0, be0, prm, N);
        k_bn_relu<<<2048, 256, 0, stream>>>(B, A, prm, N);

        k_gemm<FHID><<<gemm_blocks, 256, 0, stream>>>(A, W1, B, N);
        k_gather<<<gather_blocks, 256, 0, stream>>>(B, out, rowptr, recs, dinv, b1, N);
        hipMemsetAsync(stats, 0, 256 * sizeof(float), stream);
        k_stats<<<1024, 256, 0, stream>>>(out, stats, N);
        k_bn_params<<<1, 128, 0, stream>>>(stats, g1, be1, prm, N);
        k_bn_relu<<<2048, 256, 0, stream>>>(out, out, prm, N);
    } else {
        hipMemsetAsync(dinv, 0, (size_t)N * sizeof(float), stream);
        k_deg_hist<<<(E + 255) / 256, 256, 0, stream>>>(ei, ew, dinv, cnt, E);
        k_dinv<<<(N + 255) / 256, 256, 0, stream>>>(dinv, N);
        const int epw = 8;
        const int scatter_blocks = ((E + epw - 1) / epw + 3) / 4;

        k_gemm<FIN><<<gemm_blocks, 256, 0, stream>>>(x, W0, A, N);
        k_init_agg<<<2048, 256, 0, stream>>>(A, dinv, b0, B, N);
        k_scatter<<<scatter_blocks, 256, 0, stream>>>(A, B, ei, ew, dinv, E, epw);
        hipMemsetAsync(stats, 0, 256 * sizeof(float), stream);
        k_stats<<<1024, 256, 0, stream>>>(B, stats, N);
        k_bn_params<<<1, 128, 0, stream>>>(stats, g0, be0, prm, N);
        k_bn_relu<<<2048, 256, 0, stream>>>(B, A, prm, N);

        k_gemm<FHID><<<gemm_blocks, 256, 0, stream>>>(A, W1, B, N);
        k_init_agg<<<2048, 256, 0, stream>>>(B, dinv, b1, out, N);
        k_scatter<<<scatter_blocks, 256, 0, stream>>>(B, out, ei, ew, dinv, E, epw);
        hipMemsetAsync(stats, 0, 256 * sizeof(float), stream);
        k_stats<<<1024, 256, 0, stream>>>(out, stats, N);
        k_bn_params<<<1, 128, 0, stream>>>(stats, g1, be1, prm, N);
        k_bn_relu<<<2048, 256, 0, stream>>>(out, out, prm, N);
    }
}

// Round 3
// 628.395 us; speedup vs baseline: 4.7447x; 1.2734x over previous
//
#include <hip/hip_runtime.h>
#include <stdint.h>

#define FIN 256
#define FHID 128
#define BN_EPS 1e-3f

typedef short bf16x8 __attribute__((ext_vector_type(8)));
typedef float f32x4 __attribute__((ext_vector_type(4)));

__device__ inline short f2bf(float f) {
    unsigned u = __float_as_uint(f);
    unsigned r = (u + 0x7FFFu + ((u >> 16) & 1u)) >> 16;   // RNE
    return (short)r;
}
__device__ inline float bflo(unsigned v) { return __uint_as_float(v << 16); }
__device__ inline float bfhi(unsigned v) { return __uint_as_float(v & 0xFFFF0000u); }

// ---------------- W -> Wt (bf16, transposed [n][k]) ----------------
__global__ __launch_bounds__(256) void k_prep_w(const float* __restrict__ W,
                                                short* __restrict__ Wt, int logK) {
    int idx = blockIdx.x * 256 + threadIdx.x;
    int K = 1 << logK;
    if (idx < (K << 7)) {
        int n = idx >> logK;
        int k = idx & (K - 1);
        Wt[idx] = f2bf(W[(k << 7) + n]);
    }
}

// ---------------- packed degree+count histogram ----------------
__global__ __launch_bounds__(256) void k_deg_hist(const int* __restrict__ ei,
                                                  const float* __restrict__ ew,
                                                  unsigned long long* __restrict__ pk, int E) {
    int e = blockIdx.x * blockDim.x + threadIdx.x;
    if (e < E) {
        int dst = ei[E + e];
        unsigned long long v = (1ull << 40) |
            (unsigned long long)(ew[e] * 16777216.0f);   // 2^24 fixed point
        atomicAdd(&pk[dst], v);
    }
}

__global__ __launch_bounds__(256) void k_dinv_unpack(const unsigned long long* __restrict__ pk,
                                                     float* __restrict__ dinv,
                                                     int* __restrict__ cnt, int n) {
    int i = blockIdx.x * 256 + threadIdx.x;
    if (i < n) {
        unsigned long long v = pk[i];
        cnt[i] = (int)(v >> 40);
        float deg = (float)(v & 0xFFFFFFFFFFull) * (1.0f / 16777216.0f) + 1.0f;
        dinv[i] = rsqrtf(deg);
    }
}

// ---------------- exclusive scan (3-kernel) ----------------
__global__ __launch_bounds__(256) void k_scan_block(const int* __restrict__ cnt,
                                                    int* __restrict__ rowptr,
                                                    int* __restrict__ bsums, int n) {
    __shared__ int lds[256];
    const int base = blockIdx.x * 1024;
    const int t = threadIdx.x;
    int v[4];
    int s = 0;
#pragma unroll
    for (int i = 0; i < 4; i++) {
        int idx = base + t * 4 + i;
        v[i] = (idx < n) ? cnt[idx] : 0;
        s += v[i];
    }
    lds[t] = s;
    __syncthreads();
    for (int off = 1; off < 256; off <<= 1) {
        int add = (t >= off) ? lds[t - off] : 0;
        __syncthreads();
        lds[t] += add;
        __syncthreads();
    }
    int run = lds[t] - s;
#pragma unroll
    for (int i = 0; i < 4; i++) {
        int idx = base + t * 4 + i;
        if (idx < n) rowptr[idx] = run;
        run += v[i];
    }
    if (t == 255) bsums[blockIdx.x] = lds[255];
}

__global__ void k_scan_sums(int* bsums, int nb) {
    if (threadIdx.x == 0 && blockIdx.x == 0) {
        int run = 0;
        for (int i = 0; i < nb; i++) { int v = bsums[i]; bsums[i] = run; run += v; }
    }
}

__global__ __launch_bounds__(256) void k_scan_apply(int* __restrict__ rowptr,
                                                    const int* __restrict__ bsums,
                                                    int n, int E) {
    int idx = blockIdx.x * 256 + threadIdx.x;
    if (idx < n) rowptr[idx] += bsums[idx >> 10];
    if (idx == n) rowptr[n] = E;
}

// ---------------- CSR fill ----------------
__global__ __launch_bounds__(256) void k_fill(const int* __restrict__ ei,
                                              const float* __restrict__ ew,
                                              const float* __restrict__ dinv,
                                              const int* __restrict__ rowptr,
                                              int* __restrict__ cnt,
                                              int2* __restrict__ recs, int E) {
    int e = blockIdx.x * blockDim.x + threadIdx.x;
    if (e < E) {
        int src = ei[e];
        int dst = ei[E + e];
        int slot = atomicSub(&cnt[dst], 1) - 1;
        int pos = rowptr[dst] + slot;
        float norm = dinv[src] * ew[e] * dinv[dst];
        recs[pos] = make_int2(src, __float_as_int(norm));
    }
}

// ---------------- MFMA GEMM: H_bf16[n,128] = X[n,K] * Wt^T ----------------
// Wt is [128][K] bf16 (i.e. W transposed). Zero LDS, zero syncs.
// Block = 4 waves; wave w covers cols [w*32, w*32+32); block covers 32 rows.
template <int K, bool INF32>
__global__ __launch_bounds__(256) void k_gemm_mfma(const void* __restrict__ Xv,
                                                   const short* __restrict__ Wt,
                                                   short* __restrict__ H, int nrows) {
    constexpr int KS = K / 32;
    const int lane = threadIdx.x & 63;
    const int w = threadIdx.x >> 6;
    const int r0 = blockIdx.x * 32;
    const int n0 = w * 32;
    const int l15 = lane & 15;
    const int lk = (lane >> 4) * 8;

    // B fragments resident in registers: b[ks][nf]
    bf16x8 b[KS][2];
#pragma unroll
    for (int ks = 0; ks < KS; ks++)
#pragma unroll
        for (int nf = 0; nf < 2; nf++)
            b[ks][nf] = *reinterpret_cast<const bf16x8*>(
                Wt + (size_t)(n0 + nf * 16 + l15) * K + ks * 32 + lk);

    f32x4 acc[2][2];
#pragma unroll
    for (int mf = 0; mf < 2; mf++)
#pragma unroll
        for (int nf = 0; nf < 2; nf++)
#pragma unroll
            for (int r = 0; r < 4; r++) acc[mf][nf][r] = 0.0f;

#pragma unroll
    for (int ks = 0; ks < KS; ks++) {
        bf16x8 a[2];
#pragma unroll
        for (int mf = 0; mf < 2; mf++) {
            int row = r0 + mf * 16 + l15;
            if (row >= nrows) row = nrows - 1;
            if (INF32) {
                const float* p = (const float*)Xv + (size_t)row * K + ks * 32 + lk;
                const float4 u0 = *reinterpret_cast<const float4*>(p);
                const float4 u1 = *reinterpret_cast<const float4*>(p + 4);
                bf16x8 t;
                t[0] = f2bf(u0.x); t[1] = f2bf(u0.y); t[2] = f2bf(u0.z); t[3] = f2bf(u0.w);
                t[4] = f2bf(u1.x); t[5] = f2bf(u1.y); t[6] = f2bf(u1.z); t[7] = f2bf(u1.w);
                a[mf] = t;
            } else {
                a[mf] = *reinterpret_cast<const bf16x8*>(
                    (const short*)Xv + (size_t)row * K + ks * 32 + lk);
            }
        }
#pragma unroll
        for (int mf = 0; mf < 2; mf++)
#pragma unroll
            for (int nf = 0; nf < 2; nf++)
                acc[mf][nf] = __builtin_amdgcn_mfma_f32_16x16x32_bf16(
                    a[mf], b[ks][nf], acc[mf][nf], 0, 0, 0);
    }

#pragma unroll
    for (int mf = 0; mf < 2; mf++) {
        const int rbase = r0 + mf * 16 + (lane >> 4) * 4;
#pragma unroll
        for (int r = 0; r < 4; r++) {
            const int row = rbase + r;
            if (row < nrows) {
#pragma unroll
                for (int nf = 0; nf < 2; nf++)
                    H[(size_t)row * 128 + n0 + nf * 16 + l15] = f2bf(acc[mf][nf][r]);
            }
        }
    }
}

// ---------------- gather (bf16 h, fused self-loop + bias) ----------------
__global__ __launch_bounds__(256) void k_gather(const short* __restrict__ h,
                                                float* __restrict__ agg,
                                                const int* __restrict__ rowptr,
                                                const int2* __restrict__ recs,
                                                const float* __restrict__ dinv,
                                                const float* __restrict__ bias, int n) {
    const int node = (int)((blockIdx.x * (size_t)blockDim.x + threadIdx.x) >> 6);
    if (node >= n) return;
    const int f = (threadIdx.x & 63) * 2;
    const float di = dinv[node];
    const float s = di * di;
    const unsigned hv = *reinterpret_cast<const unsigned*>(h + (size_t)node * 128 + f);
    const float2 bv = *reinterpret_cast<const float2*>(bias + f);
    float ax = bflo(hv) * s + bv.x;
    float ay = bfhi(hv) * s + bv.y;
    int e = rowptr[node];
    const int end = rowptr[node + 1];
    for (; e + 1 < end; e += 2) {
        const int2 r0 = recs[e];
        const int2 r1 = recs[e + 1];
        const unsigned v0 = *reinterpret_cast<const unsigned*>(h + (size_t)r0.x * 128 + f);
        const unsigned v1 = *reinterpret_cast<const unsigned*>(h + (size_t)r1.x * 128 + f);
        const float n0 = __int_as_float(r0.y);
        const float n1 = __int_as_float(r1.y);
        ax += bflo(v0) * n0; ay += bfhi(v0) * n0;
        ax += bflo(v1) * n1; ay += bfhi(v1) * n1;
    }
    if (e < end) {
        const int2 r0 = recs[e];
        const unsigned v0 = *reinterpret_cast<const unsigned*>(h + (size_t)r0.x * 128 + f);
        const float n0 = __int_as_float(r0.y);
        ax += bflo(v0) * n0; ay += bfhi(v0) * n0;
    }
    *reinterpret_cast<float2*>(agg + (size_t)node * 128 + f) = make_float2(ax, ay);
}

// ---------------- per-feature sum / sumsq ----------------
__global__ __launch_bounds__(256) void k_stats(const float* __restrict__ x,
                                               float* __restrict__ stats, int n) {
    __shared__ float sdata[512];
    const int t = threadIdx.x;
    const int f = t & 127;
    float ls = 0.f, lsq = 0.f;
    for (int node = blockIdx.x * 2 + (t >> 7); node < n; node += gridDim.x * 2) {
        float v = x[(size_t)node * 128 + f];
        ls += v;
        lsq += v * v;
    }
    sdata[t] = ls;
    sdata[256 + t] = lsq;
    __syncthreads();
    if (t < 128) {
        atomicAdd(&stats[f], sdata[t] + sdata[t + 128]);
        atomicAdd(&stats[128 + f], sdata[256 + t] + sdata[256 + t + 128]);
    }
}

__global__ void k_bn_params(const float* __restrict__ stats,
                            const float* __restrict__ g,
                            const float* __restrict__ beta,
                            float* __restrict__ prm, int n) {
    int f = threadIdx.x;
    float inv_n = 1.0f / (float)n;
    float mu = stats[f] * inv_n;
    float var = stats[128 + f] * inv_n - mu * mu;
    float sc = rsqrtf(var + BN_EPS) * g[f];
    prm[f] = sc;
    prm[128 + f] = beta[f] - mu * sc;
}

// ---------------- BN apply + ReLU (templated output) ----------------
template <bool BF16OUT>
__global__ __launch_bounds__(256) void k_bn_relu(const float* __restrict__ x,
                                                 void* __restrict__ yv,
                                                 const float* __restrict__ prm, int n) {
    int idx = blockIdx.x * blockDim.x + threadIdx.x;
    const int total = n * 32;
    for (; idx < total; idx += gridDim.x * blockDim.x) {
        int node = idx >> 5;
        int c4 = (idx & 31) * 4;
        const float4 xv = *reinterpret_cast<const float4*>(x + (size_t)node * 128 + c4);
        const float4 sc = *reinterpret_cast<const float4*>(prm + c4);
        const float4 sh = *reinterpret_cast<const float4*>(prm + 128 + c4);
        float4 o;
        o.x = fmaxf(xv.x * sc.x + sh.x, 0.f);
        o.y = fmaxf(xv.y * sc.y + sh.y, 0.f);
        o.z = fmaxf(xv.z * sc.z + sh.z, 0.f);
        o.w = fmaxf(xv.w * sc.w + sh.w, 0.f);
        if (BF16OUT) {
            short* y = (short*)yv;
            *reinterpret_cast<short4*>(y + (size_t)node * 128 + c4) =
                make_short4(f2bf(o.x), f2bf(o.y), f2bf(o.z), f2bf(o.w));
        } else {
            float* y = (float*)yv;
            *reinterpret_cast<float4*>(y + (size_t)node * 128 + c4) = o;
        }
    }
}

extern "C" void kernel_launch(void* const* d_in, const int* in_sizes, int n_in,
                              void* d_out, int out_size, void* d_ws, size_t ws_size,
                              hipStream_t stream) {
    const float* x   = (const float*)d_in[0];
    const int*   ei  = (const int*)d_in[1];
    const float* ew  = (const float*)d_in[2];
    const float* W0  = (const float*)d_in[3];
    const float* b0  = (const float*)d_in[4];
    const float* g0  = (const float*)d_in[5];
    const float* be0 = (const float*)d_in[6];
    const float* W1  = (const float*)d_in[7];
    const float* b1  = (const float*)d_in[8];
    const float* g1  = (const float*)d_in[9];
    const float* be1 = (const float*)d_in[10];
    float* out = (float*)d_out;

    const int N = in_sizes[0] / FIN;
    const int E = in_sizes[2];
    const int NB = (N + 1023) / 1024;

    // workspace layout (same footprint as round-2; pk aliases recs, Wt lives in d_out)
    float* agg    = (float*)d_ws;                       // [N,128] f32
    short* hbf    = (short*)(agg + (size_t)N * 128);    // [N,128] bf16
    short* ybf    = hbf + (size_t)N * 128;              // [N,128] bf16
    int2*  recs   = (int2*)(ybf + (size_t)N * 128);     // [E]
    unsigned long long* pk = (unsigned long long*)recs; // [N] (dead before fill writes recs)
    float* dinv   = (float*)(recs + E);                 // [N]
    int*   cnt    = (int*)(dinv + N);                   // [N]
    int*   rowptr = cnt + N;                            // [N+1]
    int*   bsums  = rowptr + N + 1;                     // [<=128]
    float* stats  = (float*)(bsums + 128);              // 256
    float* prm    = stats + 256;                        // 256

    // Wt staged in d_out: scratch until the final bn_relu overwrites it
    short* Wt0 = (short*)d_out;            // [128][256] bf16
    short* Wt1 = Wt0 + 256 * 128;          // [128][128] bf16

    const int gemm_blocks = (N + 31) / 32;
    const int gather_blocks = (N + 3) / 4;

    // ---- CSR build ----
    hipMemsetAsync(pk, 0, (size_t)N * 8, stream);
    k_prep_w<<<(256 * 128 + 255) / 256, 256, 0, stream>>>(W0, Wt0, 8);
    k_prep_w<<<(128 * 128 + 255) / 256, 256, 0, stream>>>(W1, Wt1, 7);
    k_deg_hist<<<(E + 255) / 256, 256, 0, stream>>>(ei, ew, pk, E);
    k_dinv_unpack<<<(N + 255) / 256, 256, 0, stream>>>(pk, dinv, cnt, N);
    k_scan_block<<<NB, 256, 0, stream>>>(cnt, rowptr, bsums, N);
    k_scan_sums<<<1, 64, 0, stream>>>(bsums, NB);
    k_scan_apply<<<(N + 256) / 256, 256, 0, stream>>>(rowptr, bsums, N, E);
    k_fill<<<(E + 255) / 256, 256, 0, stream>>>(ei, ew, dinv, rowptr, cnt, recs, E);

    // ---- layer 0 ----
    k_gemm_mfma<FIN, true><<<gemm_blocks, 256, 0, stream>>>(x, Wt0, hbf, N);
    k_gather<<<gather_blocks, 256, 0, stream>>>(hbf, agg, rowptr, recs, dinv, b0, N);
    hipMemsetAsync(stats, 0, 256 * sizeof(float), stream);
    k_stats<<<1024, 256, 0, stream>>>(agg, stats, N);
    k_bn_params<<<1, 128, 0, stream>>>(stats, g0, be0, prm, N);
    k_bn_relu<true><<<2048, 256, 0, stream>>>(agg, ybf, prm, N);

    // ---- layer 1 ----
    k_gemm_mfma<FHID, false><<<gemm_blocks, 256, 0, stream>>>(ybf, Wt1, hbf, N);
    k_gather<<<gather_blocks, 256, 0, stream>>>(hbf, agg, rowptr, recs, dinv, b1, N);
    hipMemsetAsync(stats, 0, 256 * sizeof(float), stream);
    k_stats<<<1024, 256, 0, stream>>>(agg, stats, N);
    k_bn_params<<<1, 128, 0, stream>>>(stats, g1, be1, prm, N);
    k_bn_relu<false><<<2048, 256, 0, stream>>>(agg, out, prm, N);
}

// Round 4
// 456.419 us; speedup vs baseline: 6.5324x; 1.3768x over previous
//
#include <hip/hip_runtime.h>
#include <stdint.h>

#define FIN 256
#define FHID 128
#define BN_EPS 1e-3f

typedef short bf16x8 __attribute__((ext_vector_type(8)));
typedef float f32x4 __attribute__((ext_vector_type(4)));

__device__ inline short f2bf(float f) {
    unsigned u = __float_as_uint(f);
    unsigned r = (u + 0x7FFFu + ((u >> 16) & 1u)) >> 16;   // RNE
    return (short)r;
}
__device__ inline float bflo(unsigned v) { return __uint_as_float(v << 16); }
__device__ inline float bfhi(unsigned v) { return __uint_as_float(v & 0xFFFF0000u); }

// ---------------- W0,W1 -> bf16 transposed [n][k] (one launch) ----------------
__global__ __launch_bounds__(256) void k_prep_w2(const float* __restrict__ W0,
                                                 const float* __restrict__ W1,
                                                 short* __restrict__ Wt0,
                                                 short* __restrict__ Wt1) {
    int idx = blockIdx.x * 256 + threadIdx.x;
    if (idx < 32768) {            // W0: [256][128] -> Wt0 [128][256]
        int n = idx >> 8, k = idx & 255;
        Wt0[idx] = f2bf(W0[k * 128 + n]);
    } else {
        int j = idx - 32768;      // W1: [128][128] -> Wt1 [128][128]
        if (j < 16384) {
            int n = j >> 7, k = j & 127;
            Wt1[j] = f2bf(W1[k * 128 + n]);
        }
    }
}

// ---------------- MFMA GEMM core (device) ----------------
// H_bf16[n,128] = act(X[n,K]) * Wt^T ; Wt is [128][K] bf16.
// Block = 4 waves; wave w covers cols [w*32,w*32+32); block covers 32 rows.
// BN: apply per-feature affine+relu to f32 input before bf16 convert.
template <int K, bool INF32, bool BN>
__device__ __forceinline__ void gemm_core(int bid, const void* __restrict__ Xv,
                                          const short* __restrict__ Wt,
                                          const float* __restrict__ prm,
                                          short* __restrict__ H, int nrows) {
    constexpr int KS = K / 32;
    const int lane = threadIdx.x & 63;
    const int w = threadIdx.x >> 6;
    const int r0 = bid * 32;
    const int n0 = w * 32;
    const int l15 = lane & 15;
    const int lk = (lane >> 4) * 8;

    bf16x8 b[KS][2];
#pragma unroll
    for (int ks = 0; ks < KS; ks++)
#pragma unroll
        for (int nf = 0; nf < 2; nf++)
            b[ks][nf] = *reinterpret_cast<const bf16x8*>(
                Wt + (size_t)(n0 + nf * 16 + l15) * K + ks * 32 + lk);

    f32x4 acc[2][2];
#pragma unroll
    for (int mf = 0; mf < 2; mf++)
#pragma unroll
        for (int nf = 0; nf < 2; nf++)
#pragma unroll
            for (int r = 0; r < 4; r++) acc[mf][nf][r] = 0.0f;

#pragma unroll
    for (int ks = 0; ks < KS; ks++) {
        float4 sc0, sc1, sh0, sh1;
        if (BN) {
            const int kb = ks * 32 + lk;
            sc0 = *reinterpret_cast<const float4*>(prm + kb);
            sc1 = *reinterpret_cast<const float4*>(prm + kb + 4);
            sh0 = *reinterpret_cast<const float4*>(prm + 128 + kb);
            sh1 = *reinterpret_cast<const float4*>(prm + 128 + kb + 4);
        }
        bf16x8 a[2];
#pragma unroll
        for (int mf = 0; mf < 2; mf++) {
            int row = r0 + mf * 16 + l15;
            if (row >= nrows) row = nrows - 1;
            if (INF32) {
                const float* p = (const float*)Xv + (size_t)row * K + ks * 32 + lk;
                float4 u0 = *reinterpret_cast<const float4*>(p);
                float4 u1 = *reinterpret_cast<const float4*>(p + 4);
                if (BN) {
                    u0.x = fmaxf(u0.x * sc0.x + sh0.x, 0.f);
                    u0.y = fmaxf(u0.y * sc0.y + sh0.y, 0.f);
                    u0.z = fmaxf(u0.z * sc0.z + sh0.z, 0.f);
                    u0.w = fmaxf(u0.w * sc0.w + sh0.w, 0.f);
                    u1.x = fmaxf(u1.x * sc1.x + sh1.x, 0.f);
                    u1.y = fmaxf(u1.y * sc1.y + sh1.y, 0.f);
                    u1.z = fmaxf(u1.z * sc1.z + sh1.z, 0.f);
                    u1.w = fmaxf(u1.w * sc1.w + sh1.w, 0.f);
                }
                bf16x8 t;
                t[0] = f2bf(u0.x); t[1] = f2bf(u0.y); t[2] = f2bf(u0.z); t[3] = f2bf(u0.w);
                t[4] = f2bf(u1.x); t[5] = f2bf(u1.y); t[6] = f2bf(u1.z); t[7] = f2bf(u1.w);
                a[mf] = t;
            } else {
                a[mf] = *reinterpret_cast<const bf16x8*>(
                    (const short*)Xv + (size_t)row * K + ks * 32 + lk);
            }
        }
#pragma unroll
        for (int mf = 0; mf < 2; mf++)
#pragma unroll
            for (int nf = 0; nf < 2; nf++)
                acc[mf][nf] = __builtin_amdgcn_mfma_f32_16x16x32_bf16(
                    a[mf], b[ks][nf], acc[mf][nf], 0, 0, 0);
    }

#pragma unroll
    for (int mf = 0; mf < 2; mf++) {
        const int rbase = r0 + mf * 16 + (lane >> 4) * 4;
#pragma unroll
        for (int r = 0; r < 4; r++) {
            const int row = rbase + r;
            if (row < nrows) {
#pragma unroll
                for (int nf = 0; nf < 2; nf++)
                    H[(size_t)row * 128 + n0 + nf * 16 + l15] = f2bf(acc[mf][nf][r]);
            }
        }
    }
}

// ---------------- combo: deg_hist (+slot capture)  ||  gemm0 ----------------
__global__ __launch_bounds__(256) void k_combo(const int* __restrict__ ei,
                                               const float* __restrict__ ew,
                                               unsigned long long* __restrict__ pk,
                                               int* __restrict__ eslot, int E,
                                               int histBlocks,
                                               const float* __restrict__ x,
                                               const short* __restrict__ Wt0,
                                               short* __restrict__ H, int nrows) {
    if ((int)blockIdx.x < histBlocks) {
        int e = blockIdx.x * 256 + threadIdx.x;
        if (e < E) {
            int dst = ei[E + e];
            unsigned long long v = (1ull << 40) |
                (unsigned long long)(ew[e] * 16777216.0f);   // 2^24 fixed point
            unsigned long long old = atomicAdd(&pk[dst], v);
            eslot[e] = (int)(old >> 40);                      // this edge's CSR slot
        }
    } else {
        gemm_core<FIN, true, false>(blockIdx.x - histBlocks, x, Wt0, nullptr, H, nrows);
    }
}

// ---------------- standalone GEMM layer 1 (BN0+ReLU fused on A-load) -------
__global__ __launch_bounds__(256) void k_gemm1(const float* __restrict__ X,
                                               const short* __restrict__ Wt,
                                               const float* __restrict__ prm,
                                               short* __restrict__ H, int nrows) {
    gemm_core<FHID, true, true>(blockIdx.x, X, Wt, prm, H, nrows);
}

// ---------------- block scan over cnt (from pk) + dinv ----------------
__global__ __launch_bounds__(256) void k_scan_block(const unsigned long long* __restrict__ pk,
                                                    int* __restrict__ rowptr,
                                                    int* __restrict__ bsums,
                                                    float* __restrict__ dinv, int n) {
    __shared__ int lds[256];
    const int base = blockIdx.x * 1024;
    const int t = threadIdx.x;
    int v[4];
    int s = 0;
#pragma unroll
    for (int i = 0; i < 4; i++) {
        int idx = base + t * 4 + i;
        if (idx < n) {
            unsigned long long p = pk[idx];
            v[i] = (int)(p >> 40);
            float deg = (float)(p & 0xFFFFFFFFFFull) * (1.0f / 16777216.0f) + 1.0f;
            dinv[idx] = rsqrtf(deg);
        } else v[i] = 0;
        s += v[i];
    }
    lds[t] = s;
    __syncthreads();
    for (int off = 1; off < 256; off <<= 1) {
        int add = (t >= off) ? lds[t - off] : 0;
        __syncthreads();
        lds[t] += add;
        __syncthreads();
    }
    int run = lds[t] - s;
#pragma unroll
    for (int i = 0; i < 4; i++) {
        int idx = base + t * 4 + i;
        if (idx < n) rowptr[idx] = run;
        run += v[i];
    }
    if (t == 255) bsums[blockIdx.x] = lds[255];
}

// ---------------- apply block offsets (bsums scanned in-kernel) ----------------
__global__ __launch_bounds__(256) void k_scan_apply(int* __restrict__ rowptr,
                                                    const int* __restrict__ bsums,
                                                    int n, int E, int nb) {
    __shared__ int so[128], si[128];
    const int t = threadIdx.x;
    if (t < 128) {
        int val = (t < nb) ? bsums[t] : 0;
        so[t] = val;
        si[t] = val;
    }
    __syncthreads();
    for (int off = 1; off < 128; off <<= 1) {
        int add = (t < 128 && t >= off) ? si[t - off] : 0;
        __syncthreads();
        if (t < 128) si[t] += add;
        __syncthreads();
    }
    int idx = blockIdx.x * 256 + t;
    if (idx < n) {
        int c = idx >> 10;
        rowptr[idx] += si[c] - so[c];   // exclusive prefix of block sums
    }
    if (idx == n) rowptr[n] = E;
}

// ---------------- CSR fill (atomic-free via eslot) ----------------
__global__ __launch_bounds__(256) void k_fill(const int* __restrict__ ei,
                                              const float* __restrict__ ew,
                                              const float* __restrict__ dinv,
                                              const int* __restrict__ rowptr,
                                              const int* __restrict__ eslot,
                                              int2* __restrict__ recs, int E) {
    int e = blockIdx.x * blockDim.x + threadIdx.x;
    if (e < E) {
        int src = ei[e];
        int dst = ei[E + e];
        int pos = rowptr[dst] + eslot[e];
        float norm = dinv[src] * ew[e] * dinv[dst];
        recs[pos] = make_int2(src, __float_as_int(norm));
    }
}

// ---------------- gather + fused per-feature stats ----------------
__global__ __launch_bounds__(256) void k_gather_stats(const short* __restrict__ h,
                                                      float* __restrict__ agg,
                                                      const int* __restrict__ rowptr,
                                                      const int2* __restrict__ recs,
                                                      const float* __restrict__ dinv,
                                                      const float* __restrict__ bias,
                                                      float* __restrict__ partial,
                                                      int n, int nwaves) {
    __shared__ float lsum[4][128], lsq[4][128];
    const int w = threadIdx.x >> 6;
    const int l = threadIdx.x & 63;
    const int f = l * 2;
    const float2 bv = *reinterpret_cast<const float2*>(bias + f);
    float s0 = 0.f, s1 = 0.f, q0 = 0.f, q1 = 0.f;

    for (int node = blockIdx.x * 4 + w; node < n; node += nwaves) {
        const float di = dinv[node];
        const float sl = di * di;
        const unsigned hv = *reinterpret_cast<const unsigned*>(h + (size_t)node * 128 + f);
        float ax = bflo(hv) * sl + bv.x;
        float ay = bfhi(hv) * sl + bv.y;
        int e = rowptr[node];
        const int end = rowptr[node + 1];
        for (; e + 3 < end; e += 4) {
            const int2 r0 = recs[e];
            const int2 r1 = recs[e + 1];
            const int2 r2 = recs[e + 2];
            const int2 r3 = recs[e + 3];
            const unsigned v0 = *reinterpret_cast<const unsigned*>(h + (size_t)r0.x * 128 + f);
            const unsigned v1 = *reinterpret_cast<const unsigned*>(h + (size_t)r1.x * 128 + f);
            const unsigned v2 = *reinterpret_cast<const unsigned*>(h + (size_t)r2.x * 128 + f);
            const unsigned v3 = *reinterpret_cast<const unsigned*>(h + (size_t)r3.x * 128 + f);
            const float n0 = __int_as_float(r0.y);
            const float n1 = __int_as_float(r1.y);
            const float n2 = __int_as_float(r2.y);
            const float n3 = __int_as_float(r3.y);
            ax += bflo(v0) * n0; ay += bfhi(v0) * n0;
            ax += bflo(v1) * n1; ay += bfhi(v1) * n1;
            ax += bflo(v2) * n2; ay += bfhi(v2) * n2;
            ax += bflo(v3) * n3; ay += bfhi(v3) * n3;
        }
        for (; e < end; e++) {
            const int2 r0 = recs[e];
            const unsigned v0 = *reinterpret_cast<const unsigned*>(h + (size_t)r0.x * 128 + f);
            const float n0 = __int_as_float(r0.y);
            ax += bflo(v0) * n0; ay += bfhi(v0) * n0;
        }
        *reinterpret_cast<float2*>(agg + (size_t)node * 128 + f) = make_float2(ax, ay);
        s0 += ax; q0 += ax * ax;
        s1 += ay; q1 += ay * ay;
    }

    lsum[w][f] = s0; lsum[w][f + 1] = s1;
    lsq[w][f] = q0;  lsq[w][f + 1] = q1;
    __syncthreads();
    const int t = threadIdx.x;
    if (t < 128) {
        float ps = lsum[0][t] + lsum[1][t] + lsum[2][t] + lsum[3][t];
        float pq = lsq[0][t] + lsq[1][t] + lsq[2][t] + lsq[3][t];
        partial[(size_t)blockIdx.x * 256 + t] = ps;
        partial[(size_t)blockIdx.x * 256 + 128 + t] = pq;
    }
}

// ---------------- reduce partials -> stats (256 floats) ----------------
__global__ __launch_bounds__(256) void k_stats_red(const float* __restrict__ partial,
                                                   float* __restrict__ stats, int nblk) {
    const int gid = blockIdx.x * 256 + threadIdx.x;   // grid = 64 blocks
    const int slot = gid & 255;
    const int chunk = gid >> 8;                        // 64 chunks
    const int per = nblk >> 6;                         // nblk/64
    float v = 0.f;
    for (int p = chunk * per; p < (chunk + 1) * per; p++)
        v += partial[(size_t)p * 256 + slot];
    atomicAdd(&stats[slot], v);
}

__global__ void k_bn_params(const float* __restrict__ stats,
                            const float* __restrict__ g,
                            const float* __restrict__ beta,
                            float* __restrict__ prm, int n) {
    int f = threadIdx.x;   // 128 threads
    float inv_n = 1.0f / (float)n;
    float mu = stats[f] * inv_n;
    float var = stats[128 + f] * inv_n - mu * mu;
    float sc = rsqrtf(var + BN_EPS) * g[f];
    prm[f] = sc;
    prm[128 + f] = beta[f] - mu * sc;
}

// ---------------- final BN apply + ReLU (f32 out) ----------------
__global__ __launch_bounds__(256) void k_bn_relu(const float* __restrict__ x,
                                                 float* __restrict__ y,
                                                 const float* __restrict__ prm, int n) {
    int idx = blockIdx.x * blockDim.x + threadIdx.x;
    const int total = n * 32;
    for (; idx < total; idx += gridDim.x * blockDim.x) {
        int node = idx >> 5;
        int c4 = (idx & 31) * 4;
        const float4 xv = *reinterpret_cast<const float4*>(x + (size_t)node * 128 + c4);
        const float4 sc = *reinterpret_cast<const float4*>(prm + c4);
        const float4 sh = *reinterpret_cast<const float4*>(prm + 128 + c4);
        float4 o;
        o.x = fmaxf(xv.x * sc.x + sh.x, 0.f);
        o.y = fmaxf(xv.y * sc.y + sh.y, 0.f);
        o.z = fmaxf(xv.z * sc.z + sh.z, 0.f);
        o.w = fmaxf(xv.w * sc.w + sh.w, 0.f);
        *reinterpret_cast<float4*>(y + (size_t)node * 128 + c4) = o;
    }
}

extern "C" void kernel_launch(void* const* d_in, const int* in_sizes, int n_in,
                              void* d_out, int out_size, void* d_ws, size_t ws_size,
                              hipStream_t stream) {
    const float* x   = (const float*)d_in[0];
    const int*   ei  = (const int*)d_in[1];
    const float* ew  = (const float*)d_in[2];
    const float* W0  = (const float*)d_in[3];
    const float* b0  = (const float*)d_in[4];
    const float* g0  = (const float*)d_in[5];
    const float* be0 = (const float*)d_in[6];
    const float* W1  = (const float*)d_in[7];
    const float* b1  = (const float*)d_in[8];
    const float* g1  = (const float*)d_in[9];
    const float* be1 = (const float*)d_in[10];
    float* out = (float*)d_out;

    const int N = in_sizes[0] / FIN;     // 100000
    const int E = in_sizes[2];           // 1600000
    const int NB = (N + 1023) / 1024;    // scan blocks (98)

    const int GB = 2048;                 // gather grid
    // workspace layout
    float* agg    = (float*)d_ws;                        // [N,128] f32
    short* hbf    = (short*)(agg + (size_t)N * 128);     // [N,128] bf16
    int2*  recs   = (int2*)(hbf + (size_t)N * 128);      // [E]
    unsigned long long* pk = (unsigned long long*)recs;  // [N], dead before fill
    int*   eslot  = (int*)(recs + E);                    // [E]
    float* dinv   = (float*)(eslot + E);                 // [N]
    int*   rowptr = (int*)(dinv + N);                    // [N+1]
    int*   bsums  = rowptr + N + 1;                      // [<=128]
    float* stats  = (float*)(bsums + 128);               // 512 (2 layers x 256)
    float* prm    = stats + 512;                         // 256
    float* partial= prm + 256;                           // [GB*256]
    short* Wt0    = (short*)(partial + (size_t)GB * 256);// [128][256] bf16
    short* Wt1    = Wt0 + 256 * 128;                     // [128][128] bf16

    const int gemm_blocks = (N + 31) / 32;
    const int hist_blocks = (E + 255) / 256;

    // ---- prep + CSR build (hist overlapped with gemm0) ----
    hipMemsetAsync(pk, 0, (size_t)N * 8, stream);
    hipMemsetAsync(stats, 0, 512 * sizeof(float), stream);
    k_prep_w2<<<192, 256, 0, stream>>>(W0, W1, Wt0, Wt1);
    k_combo<<<hist_blocks + gemm_blocks, 256, 0, stream>>>(
        ei, ew, pk, eslot, E, hist_blocks, x, Wt0, hbf, N);
    k_scan_block<<<NB, 256, 0, stream>>>(pk, rowptr, bsums, dinv, N);
    k_scan_apply<<<(N + 256) / 256, 256, 0, stream>>>(rowptr, bsums, N, E, NB);
    k_fill<<<hist_blocks, 256, 0, stream>>>(ei, ew, dinv, rowptr, eslot, recs, E);

    // ---- layer 0 ----
    k_gather_stats<<<GB, 256, 0, stream>>>(hbf, agg, rowptr, recs, dinv, b0,
                                           partial, N, GB * 4);
    k_stats_red<<<64, 256, 0, stream>>>(partial, stats, GB);
    k_bn_params<<<1, 128, 0, stream>>>(stats, g0, be0, prm, N);

    // ---- layer 1 (BN0+ReLU fused into GEMM A-load) ----
    k_gemm1<<<gemm_blocks, 256, 0, stream>>>(agg, Wt1, prm, hbf, N);
    k_gather_stats<<<GB, 256, 0, stream>>>(hbf, agg, rowptr, recs, dinv, b1,
                                           partial, N, GB * 4);
    k_stats_red<<<64, 256, 0, stream>>>(partial, stats + 256, GB);
    k_bn_params<<<1, 128, 0, stream>>>(stats + 256, g1, be1, prm, N);
    k_bn_relu<<<2048, 256, 0, stream>>>(agg, out, prm, N);
}

// Round 5
// 436.450 us; speedup vs baseline: 6.8313x; 1.0458x over previous
//
#include <hip/hip_runtime.h>
#include <stdint.h>

#define FIN 256
#define FHID 128
#define BN_EPS 1e-3f

typedef short bf16x8 __attribute__((ext_vector_type(8)));
typedef float f32x4 __attribute__((ext_vector_type(4)));

__device__ inline short f2bf(float f) {
    unsigned u = __float_as_uint(f);
    unsigned r = (u + 0x7FFFu + ((u >> 16) & 1u)) >> 16;   // RNE
    return (short)r;
}
__device__ inline float bflo(unsigned v) { return __uint_as_float(v << 16); }
__device__ inline float bfhi(unsigned v) { return __uint_as_float(v & 0xFFFF0000u); }

#define DEG_SCALE 131072.0f          // 2^17 fixed point, range 128
#define DEG_INV   (1.0f / 131072.0f)

// ---------------- W0,W1 -> bf16 transposed [n][k] (one launch) ----------------
__global__ __launch_bounds__(256) void k_prep_w2(const float* __restrict__ W0,
                                                 const float* __restrict__ W1,
                                                 short* __restrict__ Wt0,
                                                 short* __restrict__ Wt1) {
    int idx = blockIdx.x * 256 + threadIdx.x;
    if (idx < 32768) {            // W0: [256][128] -> Wt0 [128][256]
        int n = idx >> 8, k = idx & 255;
        Wt0[idx] = f2bf(W0[k * 128 + n]);
    } else {
        int j = idx - 32768;      // W1: [128][128] -> Wt1 [128][128]
        if (j < 16384) {
            int n = j >> 7, k = j & 127;
            Wt1[j] = f2bf(W1[k * 128 + n]);
        }
    }
}

// ---------------- MFMA GEMM core (device) ----------------
template <int K, bool INF32, bool BN>
__device__ __forceinline__ void gemm_core(int bid, const void* __restrict__ Xv,
                                          const short* __restrict__ Wt,
                                          const float* __restrict__ prm,
                                          short* __restrict__ H, int nrows) {
    constexpr int KS = K / 32;
    const int lane = threadIdx.x & 63;
    const int w = threadIdx.x >> 6;
    const int r0 = bid * 32;
    const int n0 = w * 32;
    const int l15 = lane & 15;
    const int lk = (lane >> 4) * 8;

    bf16x8 b[KS][2];
#pragma unroll
    for (int ks = 0; ks < KS; ks++)
#pragma unroll
        for (int nf = 0; nf < 2; nf++)
            b[ks][nf] = *reinterpret_cast<const bf16x8*>(
                Wt + (size_t)(n0 + nf * 16 + l15) * K + ks * 32 + lk);

    f32x4 acc[2][2];
#pragma unroll
    for (int mf = 0; mf < 2; mf++)
#pragma unroll
        for (int nf = 0; nf < 2; nf++)
#pragma unroll
            for (int r = 0; r < 4; r++) acc[mf][nf][r] = 0.0f;

#pragma unroll
    for (int ks = 0; ks < KS; ks++) {
        float4 sc0, sc1, sh0, sh1;
        if (BN) {
            const int kb = ks * 32 + lk;
            sc0 = *reinterpret_cast<const float4*>(prm + kb);
            sc1 = *reinterpret_cast<const float4*>(prm + kb + 4);
            sh0 = *reinterpret_cast<const float4*>(prm + 128 + kb);
            sh1 = *reinterpret_cast<const float4*>(prm + 128 + kb + 4);
        }
        bf16x8 a[2];
#pragma unroll
        for (int mf = 0; mf < 2; mf++) {
            int row = r0 + mf * 16 + l15;
            if (row >= nrows) row = nrows - 1;
            if (INF32) {
                const float* p = (const float*)Xv + (size_t)row * K + ks * 32 + lk;
                float4 u0 = *reinterpret_cast<const float4*>(p);
                float4 u1 = *reinterpret_cast<const float4*>(p + 4);
                if (BN) {
                    u0.x = fmaxf(u0.x * sc0.x + sh0.x, 0.f);
                    u0.y = fmaxf(u0.y * sc0.y + sh0.y, 0.f);
                    u0.z = fmaxf(u0.z * sc0.z + sh0.z, 0.f);
                    u0.w = fmaxf(u0.w * sc0.w + sh0.w, 0.f);
                    u1.x = fmaxf(u1.x * sc1.x + sh1.x, 0.f);
                    u1.y = fmaxf(u1.y * sc1.y + sh1.y, 0.f);
                    u1.z = fmaxf(u1.z * sc1.z + sh1.z, 0.f);
                    u1.w = fmaxf(u1.w * sc1.w + sh1.w, 0.f);
                }
                bf16x8 t;
                t[0] = f2bf(u0.x); t[1] = f2bf(u0.y); t[2] = f2bf(u0.z); t[3] = f2bf(u0.w);
                t[4] = f2bf(u1.x); t[5] = f2bf(u1.y); t[6] = f2bf(u1.z); t[7] = f2bf(u1.w);
                a[mf] = t;
            } else {
                a[mf] = *reinterpret_cast<const bf16x8*>(
                    (const short*)Xv + (size_t)row * K + ks * 32 + lk);
            }
        }
#pragma unroll
        for (int mf = 0; mf < 2; mf++)
#pragma unroll
            for (int nf = 0; nf < 2; nf++)
                acc[mf][nf] = __builtin_amdgcn_mfma_f32_16x16x32_bf16(
                    a[mf], b[ks][nf], acc[mf][nf], 0, 0, 0);
    }

#pragma unroll
    for (int mf = 0; mf < 2; mf++) {
        const int rbase = r0 + mf * 16 + (lane >> 4) * 4;
#pragma unroll
        for (int r = 0; r < 4; r++) {
            const int row = rbase + r;
            if (row < nrows) {
#pragma unroll
                for (int nf = 0; nf < 2; nf++)
                    H[(size_t)row * 128 + n0 + nf * 16 + l15] = f2bf(acc[mf][nf][r]);
            }
        }
    }
}

// ---------------- combo: 32-bit packed hist (+slot capture) || gemm0 --------
__global__ __launch_bounds__(256) void k_combo(const int* __restrict__ ei,
                                               const float* __restrict__ ew,
                                               unsigned* __restrict__ pk,
                                               int* __restrict__ eslot, int E,
                                               int histBlocks,
                                               const float* __restrict__ x,
                                               const short* __restrict__ Wt0,
                                               short* __restrict__ H, int nrows) {
    if ((int)blockIdx.x < histBlocks) {
        int e = blockIdx.x * 256 + threadIdx.x;
        if (e < E) {
            int dst = ei[E + e];
            unsigned v = (1u << 24) | (unsigned)(ew[e] * DEG_SCALE);
            unsigned old = atomicAdd(&pk[dst], v);
            eslot[e] = (int)(old >> 24);             // this edge's CSR slot
        }
    } else {
        gemm_core<FIN, true, false>(blockIdx.x - histBlocks, x, Wt0, nullptr, H, nrows);
    }
}

// ---------------- standalone GEMM layer 1 (BN0+ReLU fused on A-load) -------
__global__ __launch_bounds__(256) void k_gemm1(const float* __restrict__ X,
                                               const short* __restrict__ Wt,
                                               const float* __restrict__ prm,
                                               short* __restrict__ H, int nrows) {
    gemm_core<FHID, true, true>(blockIdx.x, X, Wt, prm, H, nrows);
}

// ---------------- block scan over cnt (from pk) + dinv ----------------
__global__ __launch_bounds__(256) void k_scan_block(const unsigned* __restrict__ pk,
                                                    int* __restrict__ rowptr,
                                                    int* __restrict__ bsums,
                                                    float* __restrict__ dinv, int n) {
    __shared__ int lds[256];
    const int base = blockIdx.x * 1024;
    const int t = threadIdx.x;
    int v[4];
    int s = 0;
#pragma unroll
    for (int i = 0; i < 4; i++) {
        int idx = base + t * 4 + i;
        if (idx < n) {
            unsigned p = pk[idx];
            v[i] = (int)(p >> 24);
            float deg = (float)(p & 0xFFFFFFu) * DEG_INV + 1.0f;
            dinv[idx] = rsqrtf(deg);
        } else v[i] = 0;
        s += v[i];
    }
    lds[t] = s;
    __syncthreads();
    for (int off = 1; off < 256; off <<= 1) {
        int add = (t >= off) ? lds[t - off] : 0;
        __syncthreads();
        lds[t] += add;
        __syncthreads();
    }
    int run = lds[t] - s;
#pragma unroll
    for (int i = 0; i < 4; i++) {
        int idx = base + t * 4 + i;
        if (idx < n) rowptr[idx] = run;
        run += v[i];
    }
    if (t == 255) bsums[blockIdx.x] = lds[255];
}

// ---------------- apply block offsets (bsums scanned in-kernel) ----------------
__global__ __launch_bounds__(256) void k_scan_apply(int* __restrict__ rowptr,
                                                    const int* __restrict__ bsums,
                                                    int n, int E, int nb) {
    __shared__ int so[128], si[128];
    const int t = threadIdx.x;
    if (t < 128) {
        int val = (t < nb) ? bsums[t] : 0;
        so[t] = val;
        si[t] = val;
    }
    __syncthreads();
    for (int off = 1; off < 128; off <<= 1) {
        int add = (t < 128 && t >= off) ? si[t - off] : 0;
        __syncthreads();
        if (t < 128) si[t] += add;
        __syncthreads();
    }
    int idx = blockIdx.x * 256 + t;
    if (idx < n) {
        int c = idx >> 10;
        rowptr[idx] += si[c] - so[c];
    }
    if (idx == n) rowptr[n] = E;
}

// ---------------- CSR fill (atomic-free via eslot) ----------------
__global__ __launch_bounds__(256) void k_fill(const int* __restrict__ ei,
                                              const float* __restrict__ ew,
                                              const float* __restrict__ dinv,
                                              const int* __restrict__ rowptr,
                                              const int* __restrict__ eslot,
                                              int2* __restrict__ recs, int E) {
    int e = blockIdx.x * blockDim.x + threadIdx.x;
    if (e < E) {
        int src = ei[e];
        int dst = ei[E + e];
        int pos = rowptr[dst] + eslot[e];
        float norm = dinv[src] * ew[e] * dinv[dst];
        recs[pos] = make_int2(src, __float_as_int(norm));
    }
}

// ---------------- gather + fused per-feature stats (8-deep MLP) ----------------
__global__ __launch_bounds__(256) void k_gather_stats(const short* __restrict__ h,
                                                      float* __restrict__ agg,
                                                      const int* __restrict__ rowptr,
                                                      const int4* __restrict__ recs4,
                                                      const float* __restrict__ dinv,
                                                      const float* __restrict__ bias,
                                                      float* __restrict__ partial,
                                                      int n, int nwaves) {
    __shared__ float lsum[4][128], lsq[4][128];
    const int w = threadIdx.x >> 6;
    const int l = threadIdx.x & 63;
    const int f = l * 2;
    const float2 bv = *reinterpret_cast<const float2*>(bias + f);
    float s0 = 0.f, s1 = 0.f, q0 = 0.f, q1 = 0.f;
    const int2* recs = (const int2*)recs4;

    for (int node = blockIdx.x * 4 + w; node < n; node += nwaves) {
        const float di = dinv[node];
        const float sl = di * di;
        const unsigned hv = *reinterpret_cast<const unsigned*>(h + (size_t)node * 128 + f);
        float ax = bflo(hv) * sl + bv.x;
        float ay = bfhi(hv) * sl + bv.y;
        int e = rowptr[node];
        const int end = rowptr[node + 1];
        // 8-edge unroll: 4 x int4 rec loads, 8 row-gathers in flight
        for (; e + 7 < end; e += 8) {
            // e is arbitrary parity; recs is 8B-aligned, int4 needs 16B.
            const int2 r0 = recs[e];
            const int2 r1 = recs[e + 1];
            const int2 r2 = recs[e + 2];
            const int2 r3 = recs[e + 3];
            const int2 r4 = recs[e + 4];
            const int2 r5 = recs[e + 5];
            const int2 r6 = recs[e + 6];
            const int2 r7 = recs[e + 7];
            const unsigned v0 = *reinterpret_cast<const unsigned*>(h + (size_t)r0.x * 128 + f);
            const unsigned v1 = *reinterpret_cast<const unsigned*>(h + (size_t)r1.x * 128 + f);
            const unsigned v2 = *reinterpret_cast<const unsigned*>(h + (size_t)r2.x * 128 + f);
            const unsigned v3 = *reinterpret_cast<const unsigned*>(h + (size_t)r3.x * 128 + f);
            const unsigned v4 = *reinterpret_cast<const unsigned*>(h + (size_t)r4.x * 128 + f);
            const unsigned v5 = *reinterpret_cast<const unsigned*>(h + (size_t)r5.x * 128 + f);
            const unsigned v6 = *reinterpret_cast<const unsigned*>(h + (size_t)r6.x * 128 + f);
            const unsigned v7 = *reinterpret_cast<const unsigned*>(h + (size_t)r7.x * 128 + f);
            ax += bflo(v0) * __int_as_float(r0.y); ay += bfhi(v0) * __int_as_float(r0.y);
            ax += bflo(v1) * __int_as_float(r1.y); ay += bfhi(v1) * __int_as_float(r1.y);
            ax += bflo(v2) * __int_as_float(r2.y); ay += bfhi(v2) * __int_as_float(r2.y);
            ax += bflo(v3) * __int_as_float(r3.y); ay += bfhi(v3) * __int_as_float(r3.y);
            ax += bflo(v4) * __int_as_float(r4.y); ay += bfhi(v4) * __int_as_float(r4.y);
            ax += bflo(v5) * __int_as_float(r5.y); ay += bfhi(v5) * __int_as_float(r5.y);
            ax += bflo(v6) * __int_as_float(r6.y); ay += bfhi(v6) * __int_as_float(r6.y);
            ax += bflo(v7) * __int_as_float(r7.y); ay += bfhi(v7) * __int_as_float(r7.y);
        }
        for (; e < end; e++) {
            const int2 r0 = recs[e];
            const unsigned v0 = *reinterpret_cast<const unsigned*>(h + (size_t)r0.x * 128 + f);
            const float n0 = __int_as_float(r0.y);
            ax += bflo(v0) * n0; ay += bfhi(v0) * n0;
        }
        *reinterpret_cast<float2*>(agg + (size_t)node * 128 + f) = make_float2(ax, ay);
        s0 += ax; q0 += ax * ax;
        s1 += ay; q1 += ay * ay;
    }

    lsum[w][f] = s0; lsum[w][f + 1] = s1;
    lsq[w][f] = q0;  lsq[w][f + 1] = q1;
    __syncthreads();
    const int t = threadIdx.x;
    if (t < 128) {
        float ps = lsum[0][t] + lsum[1][t] + lsum[2][t] + lsum[3][t];
        float pq = lsq[0][t] + lsq[1][t] + lsq[2][t] + lsq[3][t];
        partial[(size_t)blockIdx.x * 256 + t] = ps;
        partial[(size_t)blockIdx.x * 256 + 128 + t] = pq;
    }
}

// ---------------- reduce partials -> stats ----------------
__global__ __launch_bounds__(256) void k_stats_red(const float* __restrict__ partial,
                                                   float* __restrict__ stats, int nblk) {
    const int gid = blockIdx.x * 256 + threadIdx.x;   // grid = 64 blocks
    const int slot = gid & 255;
    const int chunk = gid >> 8;
    const int per = nblk >> 6;
    float v = 0.f;
    for (int p = chunk * per; p < (chunk + 1) * per; p++)
        v += partial[(size_t)p * 256 + slot];
    atomicAdd(&stats[slot], v);
}

__global__ void k_bn_params(const float* __restrict__ stats,
                            const float* __restrict__ g,
                            const float* __restrict__ beta,
                            float* __restrict__ prm, int n) {
    int f = threadIdx.x;
    float inv_n = 1.0f / (float)n;
    float mu = stats[f] * inv_n;
    float var = stats[128 + f] * inv_n - mu * mu;
    float sc = rsqrtf(var + BN_EPS) * g[f];
    prm[f] = sc;
    prm[128 + f] = beta[f] - mu * sc;
}

// ---------------- final BN apply + ReLU (f32 out) ----------------
__global__ __launch_bounds__(256) void k_bn_relu(const float* __restrict__ x,
                                                 float* __restrict__ y,
                                                 const float* __restrict__ prm, int n) {
    int idx = blockIdx.x * blockDim.x + threadIdx.x;
    const int total = n * 32;
    for (; idx < total; idx += gridDim.x * blockDim.x) {
        int node = idx >> 5;
        int c4 = (idx & 31) * 4;
        const float4 xv = *reinterpret_cast<const float4*>(x + (size_t)node * 128 + c4);
        const float4 sc = *reinterpret_cast<const float4*>(prm + c4);
        const float4 sh = *reinterpret_cast<const float4*>(prm + 128 + c4);
        float4 o;
        o.x = fmaxf(xv.x * sc.x + sh.x, 0.f);
        o.y = fmaxf(xv.y * sc.y + sh.y, 0.f);
        o.z = fmaxf(xv.z * sc.z + sh.z, 0.f);
        o.w = fmaxf(xv.w * sc.w + sh.w, 0.f);
        *reinterpret_cast<float4*>(y + (size_t)node * 128 + c4) = o;
    }
}

extern "C" void kernel_launch(void* const* d_in, const int* in_sizes, int n_in,
                              void* d_out, int out_size, void* d_ws, size_t ws_size,
                              hipStream_t stream) {
    const float* x   = (const float*)d_in[0];
    const int*   ei  = (const int*)d_in[1];
    const float* ew  = (const float*)d_in[2];
    const float* W0  = (const float*)d_in[3];
    const float* b0  = (const float*)d_in[4];
    const float* g0  = (const float*)d_in[5];
    const float* be0 = (const float*)d_in[6];
    const float* W1  = (const float*)d_in[7];
    const float* b1  = (const float*)d_in[8];
    const float* g1  = (const float*)d_in[9];
    const float* be1 = (const float*)d_in[10];
    float* out = (float*)d_out;

    const int N = in_sizes[0] / FIN;     // 100000
    const int E = in_sizes[2];           // 1600000
    const int NB = (N + 1023) / 1024;    // scan blocks (98)

    const int GB = 2048;                 // gather grid
    // workspace layout
    float* agg    = (float*)d_ws;                        // [N,128] f32
    short* hbf    = (short*)(agg + (size_t)N * 128);     // [N,128] bf16
    int2*  recs   = (int2*)(hbf + (size_t)N * 128);      // [E]
    unsigned* pk  = (unsigned*)recs;                     // [N], dead before fill
    int*   eslot  = (int*)(recs + E);                    // [E]
    float* dinv   = (float*)(eslot + E);                 // [N]
    int*   rowptr = (int*)(dinv + N);                    // [N+1]
    int*   bsums  = rowptr + N + 1;                      // [<=128]
    float* stats  = (float*)(bsums + 128);               // 512
    float* prm    = stats + 512;                         // 256
    float* partial= prm + 256;                           // [GB*256]
    short* Wt0    = (short*)(partial + (size_t)GB * 256);// [128][256] bf16
    short* Wt1    = Wt0 + 256 * 128;                     // [128][128] bf16

    const int gemm_blocks = (N + 31) / 32;
    const int hist_blocks = (E + 255) / 256;

    // ---- prep + CSR build (hist overlapped with gemm0) ----
    hipMemsetAsync(pk, 0, (size_t)N * 4, stream);
    hipMemsetAsync(stats, 0, 512 * sizeof(float), stream);
    k_prep_w2<<<192, 256, 0, stream>>>(W0, W1, Wt0, Wt1);
    k_combo<<<hist_blocks + gemm_blocks, 256, 0, stream>>>(
        ei, ew, pk, eslot, E, hist_blocks, x, Wt0, hbf, N);
    k_scan_block<<<NB, 256, 0, stream>>>(pk, rowptr, bsums, dinv, N);
    k_scan_apply<<<(N + 256) / 256, 256, 0, stream>>>(rowptr, bsums, N, E, NB);
    k_fill<<<hist_blocks, 256, 0, stream>>>(ei, ew, dinv, rowptr, eslot, recs, E);

    // ---- layer 0 ----
    k_gather_stats<<<GB, 256, 0, stream>>>(hbf, agg, rowptr, (const int4*)recs, dinv, b0,
                                           partial, N, GB * 4);
    k_stats_red<<<64, 256, 0, stream>>>(partial, stats, GB);
    k_bn_params<<<1, 128, 0, stream>>>(stats, g0, be0, prm, N);

    // ---- layer 1 (BN0+ReLU fused into GEMM A-load) ----
    k_gemm1<<<gemm_blocks, 256, 0, stream>>>(agg, Wt1, prm, hbf, N);
    k_gather_stats<<<GB, 256, 0, stream>>>(hbf, agg, rowptr, (const int4*)recs, dinv, b1,
                                           partial, N, GB * 4);
    k_stats_red<<<64, 256, 0, stream>>>(partial, stats + 256, GB);
    k_bn_params<<<1, 128, 0, stream>>>(stats + 256, g1, be1, prm, N);
    k_bn_relu<<<2048, 256, 0, stream>>>(agg, out, prm, N);
}

// Round 6
// 408.192 us; speedup vs baseline: 7.3042x; 1.0692x over previous
//
#include <hip/hip_runtime.h>
#include <stdint.h>

#define FIN 256
#define FHID 128
#define BN_EPS 1e-3f

typedef short bf16x8 __attribute__((ext_vector_type(8)));
typedef float f32x4 __attribute__((ext_vector_type(4)));

__device__ inline short f2bf(float f) {
    unsigned u = __float_as_uint(f);
    unsigned r = (u + 0x7FFFu + ((u >> 16) & 1u)) >> 16;   // RNE
    return (short)r;
}
__device__ inline float bflo(unsigned v) { return __uint_as_float(v << 16); }
__device__ inline float bfhi(unsigned v) { return __uint_as_float(v & 0xFFFF0000u); }

#define DEG_SCALE 131072.0f          // 2^17 fixed point
#define DEG_INV   (1.0f / 131072.0f)

// ---------------- W0,W1 -> bf16 transposed [n][k] ----------------
__global__ __launch_bounds__(256) void k_prep_w2(const float* __restrict__ W0,
                                                 const float* __restrict__ W1,
                                                 short* __restrict__ Wt0,
                                                 short* __restrict__ Wt1) {
    int idx = blockIdx.x * 256 + threadIdx.x;
    if (idx < 32768) {            // W0: [256][128] -> Wt0 [128][256]
        int n = idx >> 8, k = idx & 255;
        Wt0[idx] = f2bf(W0[k * 128 + n]);
    } else {
        int j = idx - 32768;      // W1: [128][128] -> Wt1 [128][128]
        if (j < 16384) {
            int n = j >> 7, k = j & 127;
            Wt1[j] = f2bf(W1[k * 128 + n]);
        }
    }
}

// ---------------- MFMA GEMM core ----------------
template <int K, bool INF32, bool BN>
__device__ __forceinline__ void gemm_core(int bid, const void* __restrict__ Xv,
                                          const short* __restrict__ Wt,
                                          const float* __restrict__ prm,
                                          short* __restrict__ H, int nrows) {
    constexpr int KS = K / 32;
    const int lane = threadIdx.x & 63;
    const int w = threadIdx.x >> 6;
    const int r0 = bid * 32;
    const int n0 = w * 32;
    const int l15 = lane & 15;
    const int lk = (lane >> 4) * 8;

    bf16x8 b[KS][2];
#pragma unroll
    for (int ks = 0; ks < KS; ks++)
#pragma unroll
        for (int nf = 0; nf < 2; nf++)
            b[ks][nf] = *reinterpret_cast<const bf16x8*>(
                Wt + (size_t)(n0 + nf * 16 + l15) * K + ks * 32 + lk);

    f32x4 acc[2][2];
#pragma unroll
    for (int mf = 0; mf < 2; mf++)
#pragma unroll
        for (int nf = 0; nf < 2; nf++)
#pragma unroll
            for (int r = 0; r < 4; r++) acc[mf][nf][r] = 0.0f;

#pragma unroll
    for (int ks = 0; ks < KS; ks++) {
        float4 sc0, sc1, sh0, sh1;
        if (BN) {
            const int kb = ks * 32 + lk;
            sc0 = *reinterpret_cast<const float4*>(prm + kb);
            sc1 = *reinterpret_cast<const float4*>(prm + kb + 4);
            sh0 = *reinterpret_cast<const float4*>(prm + 128 + kb);
            sh1 = *reinterpret_cast<const float4*>(prm + 128 + kb + 4);
        }
        bf16x8 a[2];
#pragma unroll
        for (int mf = 0; mf < 2; mf++) {
            int row = r0 + mf * 16 + l15;
            if (row >= nrows) row = nrows - 1;
            if (INF32) {
                const float* p = (const float*)Xv + (size_t)row * K + ks * 32 + lk;
                float4 u0 = *reinterpret_cast<const float4*>(p);
                float4 u1 = *reinterpret_cast<const float4*>(p + 4);
                if (BN) {
                    u0.x = fmaxf(u0.x * sc0.x + sh0.x, 0.f);
                    u0.y = fmaxf(u0.y * sc0.y + sh0.y, 0.f);
                    u0.z = fmaxf(u0.z * sc0.z + sh0.z, 0.f);
                    u0.w = fmaxf(u0.w * sc0.w + sh0.w, 0.f);
                    u1.x = fmaxf(u1.x * sc1.x + sh1.x, 0.f);
                    u1.y = fmaxf(u1.y * sc1.y + sh1.y, 0.f);
                    u1.z = fmaxf(u1.z * sc1.z + sh1.z, 0.f);
                    u1.w = fmaxf(u1.w * sc1.w + sh1.w, 0.f);
                }
                bf16x8 t;
                t[0] = f2bf(u0.x); t[1] = f2bf(u0.y); t[2] = f2bf(u0.z); t[3] = f2bf(u0.w);
                t[4] = f2bf(u1.x); t[5] = f2bf(u1.y); t[6] = f2bf(u1.z); t[7] = f2bf(u1.w);
                a[mf] = t;
            } else {
                a[mf] = *reinterpret_cast<const bf16x8*>(
                    (const short*)Xv + (size_t)row * K + ks * 32 + lk);
            }
        }
#pragma unroll
        for (int mf = 0; mf < 2; mf++)
#pragma unroll
            for (int nf = 0; nf < 2; nf++)
                acc[mf][nf] = __builtin_amdgcn_mfma_f32_16x16x32_bf16(
                    a[mf], b[ks][nf], acc[mf][nf], 0, 0, 0);
    }

#pragma unroll
    for (int mf = 0; mf < 2; mf++) {
        const int rbase = r0 + mf * 16 + (lane >> 4) * 4;
#pragma unroll
        for (int r = 0; r < 4; r++) {
            const int row = rbase + r;
            if (row < nrows) {
#pragma unroll
                for (int nf = 0; nf < 2; nf++)
                    H[(size_t)row * 128 + n0 + nf * 16 + l15] = f2bf(acc[mf][nf][r]);
            }
        }
    }
}

// ---------------- phase A: per-block LDS bucket histogram || gemm0 ----------
__global__ __launch_bounds__(256) void k_phaseA(const int* __restrict__ ei, int E,
                                                int CB, int CHUNK, int nbuk,
                                                unsigned* __restrict__ bcnt,
                                                const float* __restrict__ x,
                                                const short* __restrict__ Wt0,
                                                short* __restrict__ H, int nrows) {
    __shared__ unsigned hist[1024];
    if ((int)blockIdx.x < CB) {
        for (int i = threadIdx.x; i < nbuk; i += 256) hist[i] = 0;
        __syncthreads();
        const int e0 = blockIdx.x * CHUNK;
        const int e1 = min(e0 + CHUNK, E);
        for (int e = e0 + threadIdx.x; e < e1; e += 256)
            atomicAdd(&hist[ei[E + e] >> 7], 1u);
        __syncthreads();
        for (int k = threadIdx.x; k < nbuk; k += 256)
            bcnt[(size_t)k * CB + blockIdx.x] = hist[k];
    } else {
        gemm_core<FIN, true, false>(blockIdx.x - CB, x, Wt0, nullptr, H, nrows);
    }
}

// ---------------- phase B: per-bucket scan of block counts (in-place) -------
__global__ __launch_bounds__(256) void k_phaseB(unsigned* __restrict__ bcnt,
                                                unsigned* __restrict__ btotal,
                                                int CB, int nbuk) {
    __shared__ unsigned lds[256];
    const int k = blockIdx.x;
    const int t = threadIdx.x;
    unsigned v[4];
    unsigned s = 0;
#pragma unroll
    for (int i = 0; i < 4; i++) {
        int j = t * 4 + i;
        v[i] = (j < CB) ? bcnt[(size_t)k * CB + j] : 0;
        s += v[i];
    }
    lds[t] = s;
    __syncthreads();
    for (int off = 1; off < 256; off <<= 1) {
        unsigned add = (t >= off) ? lds[t - off] : 0;
        __syncthreads();
        lds[t] += add;
        __syncthreads();
    }
    unsigned run = lds[t] - s;
#pragma unroll
    for (int i = 0; i < 4; i++) {
        int j = t * 4 + i;
        if (j < CB) bcnt[(size_t)k * CB + j] = run;
        run += v[i];
    }
    if (t == 255) btotal[k] = lds[255];
}

// ---------------- bucket base scan (single block) ----------------
__global__ __launch_bounds__(256) void k_bsum(const unsigned* __restrict__ btotal,
                                              unsigned* __restrict__ bbase,
                                              int nbuk, int E) {
    __shared__ unsigned lds[256];
    const int t = threadIdx.x;
    unsigned v[4];
    unsigned s = 0;
#pragma unroll
    for (int i = 0; i < 4; i++) {
        int j = t * 4 + i;
        v[i] = (j < nbuk) ? btotal[j] : 0;
        s += v[i];
    }
    lds[t] = s;
    __syncthreads();
    for (int off = 1; off < 256; off <<= 1) {
        unsigned add = (t >= off) ? lds[t - off] : 0;
        __syncthreads();
        lds[t] += add;
        __syncthreads();
    }
    unsigned run = lds[t] - s;
#pragma unroll
    for (int i = 0; i < 4; i++) {
        int j = t * 4 + i;
        if (j < nbuk) bbase[j] = run;
        run += v[i];
    }
    if (t == 255) bbase[nbuk] = (unsigned)E;
}

// ---------------- phase C: bucket-scatter edges (LDS cursors) ----------------
__global__ __launch_bounds__(256) void k_phaseC(const int* __restrict__ ei,
                                                const float* __restrict__ ew,
                                                int E, int CB, int CHUNK, int nbuk,
                                                const unsigned* __restrict__ bcur,
                                                const unsigned* __restrict__ bbase,
                                                int2* __restrict__ recs_mid) {
    __shared__ unsigned curs[1024];
    const int b = blockIdx.x;
    for (int k = threadIdx.x; k < nbuk; k += 256)
        curs[k] = bbase[k] + bcur[(size_t)k * CB + b];
    __syncthreads();
    const int e0 = b * CHUNK;
    const int e1 = min(e0 + CHUNK, E);
    for (int e = e0 + threadIdx.x; e < e1; e += 256) {
        int src = ei[e];
        int dst = ei[E + e];
        unsigned pos = atomicAdd(&curs[dst >> 7], 1u);
        recs_mid[pos] = make_int2(src | ((dst & 127) << 17), __float_as_int(ew[e]));
    }
}

// ---------------- phase D: per-bucket dst sort, dinv, rowptr, recs ----------
__global__ __launch_bounds__(256) void k_phaseD(const int2* __restrict__ recs_mid,
                                                const unsigned* __restrict__ bbase,
                                                float* __restrict__ dinv,
                                                int* __restrict__ rowptr,
                                                int2* __restrict__ recs,
                                                int n, int E) {
    __shared__ unsigned cnt[128], wsum[128], rank[128], sc[128], base[128];
    __shared__ float dloc[128];
    const int k = blockIdx.x;
    const int t = threadIdx.x;
    if (t < 128) { cnt[t] = 0; wsum[t] = 0; rank[t] = 0; }
    __syncthreads();
    const unsigned s0 = bbase[k], s1 = bbase[k + 1];
    for (unsigned i = s0 + t; i < s1; i += 256) {
        int2 r = recs_mid[i];
        int dl = (r.x >> 17) & 127;
        atomicAdd(&cnt[dl], 1u);
        atomicAdd(&wsum[dl], (unsigned)(__int_as_float(r.y) * DEG_SCALE));
    }
    __syncthreads();
    if (t < 128) sc[t] = cnt[t];
    __syncthreads();
    for (int off = 1; off < 128; off <<= 1) {
        unsigned add = (t < 128 && t >= off) ? sc[t - off] : 0;
        __syncthreads();
        if (t < 128) sc[t] += add;
        __syncthreads();
    }
    if (t < 128) {
        unsigned excl = sc[t] - cnt[t];
        base[t] = s0 + excl;
        int dst = k * 128 + t;
        if (dst < n) {
            float deg = (float)wsum[t] * DEG_INV + 1.0f;
            float dv = rsqrtf(deg);
            dloc[t] = dv;
            dinv[dst] = dv;
            rowptr[dst] = (int)(s0 + excl);
        }
    }
    if (k == 0 && t == 0) rowptr[n] = E;
    __syncthreads();
    for (unsigned i = s0 + t; i < s1; i += 256) {
        int2 r = recs_mid[i];
        int dl = (r.x >> 17) & 127;
        unsigned rr = atomicAdd(&rank[dl], 1u);
        float w2 = __int_as_float(r.y) * dloc[dl];     // ew * dinv[dst]
        recs[base[dl] + rr] = make_int2(r.x & 0x1FFFF, __float_as_int(w2));
    }
}

// ---------------- phase E: fold dinv[src] into rec weight ----------------
__global__ __launch_bounds__(256) void k_phaseE(int2* __restrict__ recs,
                                                const float* __restrict__ dinv, int E) {
    int i = blockIdx.x * 256 + threadIdx.x;
    if (i < E) {
        int2 r = recs[i];
        float w = __int_as_float(r.y) * dinv[r.x];
        recs[i] = make_int2(r.x, __float_as_int(w));
    }
}

// ---------------- standalone GEMM layer 1 (BN0+ReLU fused) ----------------
__global__ __launch_bounds__(256) void k_gemm1(const float* __restrict__ X,
                                               const short* __restrict__ Wt,
                                               const float* __restrict__ prm,
                                               short* __restrict__ H, int nrows) {
    gemm_core<FHID, true, true>(blockIdx.x, X, Wt, prm, H, nrows);
}

// ---------------- gather + fused per-feature stats (8-deep MLP) ----------------
__global__ __launch_bounds__(256) void k_gather_stats(const short* __restrict__ h,
                                                      float* __restrict__ agg,
                                                      const int* __restrict__ rowptr,
                                                      const int2* __restrict__ recs,
                                                      const float* __restrict__ dinv,
                                                      const float* __restrict__ bias,
                                                      float* __restrict__ partial,
                                                      int n, int nwaves) {
    __shared__ float lsum[4][128], lsq[4][128];
    const int w = threadIdx.x >> 6;
    const int l = threadIdx.x & 63;
    const int f = l * 2;
    const float2 bv = *reinterpret_cast<const float2*>(bias + f);
    float s0 = 0.f, s1 = 0.f, q0 = 0.f, q1 = 0.f;

    for (int node = blockIdx.x * 4 + w; node < n; node += nwaves) {
        const float di = dinv[node];
        const float sl = di * di;
        const unsigned hv = *reinterpret_cast<const unsigned*>(h + (size_t)node * 128 + f);
        float ax = bflo(hv) * sl + bv.x;
        float ay = bfhi(hv) * sl + bv.y;
        int e = rowptr[node];
        const int end = rowptr[node + 1];
        for (; e + 7 < end; e += 8) {
            const int2 r0 = recs[e];
            const int2 r1 = recs[e + 1];
            const int2 r2 = recs[e + 2];
            const int2 r3 = recs[e + 3];
            const int2 r4 = recs[e + 4];
            const int2 r5 = recs[e + 5];
            const int2 r6 = recs[e + 6];
            const int2 r7 = recs[e + 7];
            const unsigned v0 = *reinterpret_cast<const unsigned*>(h + (size_t)r0.x * 128 + f);
            const unsigned v1 = *reinterpret_cast<const unsigned*>(h + (size_t)r1.x * 128 + f);
            const unsigned v2 = *reinterpret_cast<const unsigned*>(h + (size_t)r2.x * 128 + f);
            const unsigned v3 = *reinterpret_cast<const unsigned*>(h + (size_t)r3.x * 128 + f);
            const unsigned v4 = *reinterpret_cast<const unsigned*>(h + (size_t)r4.x * 128 + f);
            const unsigned v5 = *reinterpret_cast<const unsigned*>(h + (size_t)r5.x * 128 + f);
            const unsigned v6 = *reinterpret_cast<const unsigned*>(h + (size_t)r6.x * 128 + f);
            const unsigned v7 = *reinterpret_cast<const unsigned*>(h + (size_t)r7.x * 128 + f);
            ax += bflo(v0) * __int_as_float(r0.y); ay += bfhi(v0) * __int_as_float(r0.y);
            ax += bflo(v1) * __int_as_float(r1.y); ay += bfhi(v1) * __int_as_float(r1.y);
            ax += bflo(v2) * __int_as_float(r2.y); ay += bfhi(v2) * __int_as_float(r2.y);
            ax += bflo(v3) * __int_as_float(r3.y); ay += bfhi(v3) * __int_as_float(r3.y);
            ax += bflo(v4) * __int_as_float(r4.y); ay += bfhi(v4) * __int_as_float(r4.y);
            ax += bflo(v5) * __int_as_float(r5.y); ay += bfhi(v5) * __int_as_float(r5.y);
            ax += bflo(v6) * __int_as_float(r6.y); ay += bfhi(v6) * __int_as_float(r6.y);
            ax += bflo(v7) * __int_as_float(r7.y); ay += bfhi(v7) * __int_as_float(r7.y);
        }
        for (; e < end; e++) {
            const int2 r0 = recs[e];
            const unsigned v0 = *reinterpret_cast<const unsigned*>(h + (size_t)r0.x * 128 + f);
            const float n0 = __int_as_float(r0.y);
            ax += bflo(v0) * n0; ay += bfhi(v0) * n0;
        }
        *reinterpret_cast<float2*>(agg + (size_t)node * 128 + f) = make_float2(ax, ay);
        s0 += ax; q0 += ax * ax;
        s1 += ay; q1 += ay * ay;
    }

    lsum[w][f] = s0; lsum[w][f + 1] = s1;
    lsq[w][f] = q0;  lsq[w][f + 1] = q1;
    __syncthreads();
    const int t = threadIdx.x;
    if (t < 128) {
        float ps = lsum[0][t] + lsum[1][t] + lsum[2][t] + lsum[3][t];
        float pq = lsq[0][t] + lsq[1][t] + lsq[2][t] + lsq[3][t];
        partial[(size_t)blockIdx.x * 256 + t] = ps;
        partial[(size_t)blockIdx.x * 256 + 128 + t] = pq;
    }
}

// ---------------- reduce partials -> stats ----------------
__global__ __launch_bounds__(256) void k_stats_red(const float* __restrict__ partial,
                                                   float* __restrict__ stats, int nblk) {
    const int gid = blockIdx.x * 256 + threadIdx.x;   // grid = 64 blocks
    const int slot = gid & 255;
    const int chunk = gid >> 8;
    const int per = nblk >> 6;
    float v = 0.f;
    for (int p = chunk * per; p < (chunk + 1) * per; p++)
        v += partial[(size_t)p * 256 + slot];
    atomicAdd(&stats[slot], v);
}

__global__ void k_bn_params(const float* __restrict__ stats,
                            const float* __restrict__ g,
                            const float* __restrict__ beta,
                            float* __restrict__ prm, int n) {
    int f = threadIdx.x;
    float inv_n = 1.0f / (float)n;
    float mu = stats[f] * inv_n;
    float var = stats[128 + f] * inv_n - mu * mu;
    float sc = rsqrtf(var + BN_EPS) * g[f];
    prm[f] = sc;
    prm[128 + f] = beta[f] - mu * sc;
}

// ---------------- final BN apply + ReLU (f32 out) ----------------
__global__ __launch_bounds__(256) void k_bn_relu(const float* __restrict__ x,
                                                 float* __restrict__ y,
                                                 const float* __restrict__ prm, int n) {
    int idx = blockIdx.x * blockDim.x + threadIdx.x;
    const int total = n * 32;
    for (; idx < total; idx += gridDim.x * blockDim.x) {
        int node = idx >> 5;
        int c4 = (idx & 31) * 4;
        const float4 xv = *reinterpret_cast<const float4*>(x + (size_t)node * 128 + c4);
        const float4 sc = *reinterpret_cast<const float4*>(prm + c4);
        const float4 sh = *reinterpret_cast<const float4*>(prm + 128 + c4);
        float4 o;
        o.x = fmaxf(xv.x * sc.x + sh.x, 0.f);
        o.y = fmaxf(xv.y * sc.y + sh.y, 0.f);
        o.z = fmaxf(xv.z * sc.z + sh.z, 0.f);
        o.w = fmaxf(xv.w * sc.w + sh.w, 0.f);
        *reinterpret_cast<float4*>(y + (size_t)node * 128 + c4) = o;
    }
}

extern "C" void kernel_launch(void* const* d_in, const int* in_sizes, int n_in,
                              void* d_out, int out_size, void* d_ws, size_t ws_size,
                              hipStream_t stream) {
    const float* x   = (const float*)d_in[0];
    const int*   ei  = (const int*)d_in[1];
    const float* ew  = (const float*)d_in[2];
    const float* W0  = (const float*)d_in[3];
    const float* b0  = (const float*)d_in[4];
    const float* g0  = (const float*)d_in[5];
    const float* be0 = (const float*)d_in[6];
    const float* W1  = (const float*)d_in[7];
    const float* b1  = (const float*)d_in[8];
    const float* g1  = (const float*)d_in[9];
    const float* be1 = (const float*)d_in[10];
    float* out = (float*)d_out;

    const int N = in_sizes[0] / FIN;          // 100000
    const int E = in_sizes[2];                // 1600000
    const int NBUK = (N + 127) >> 7;          // 782
    const int CB = 800;                       // edge chunks
    const int CHUNK = (E + CB - 1) / CB;      // 2000
    const int GB = 2048;                      // gather grid

    // workspace layout (~108 MB)
    float* agg      = (float*)d_ws;                          // [N,128] f32
    short* hbf      = (short*)(agg + (size_t)N * 128);       // [N,128] bf16
    int2*  recs     = (int2*)(hbf + (size_t)N * 128);        // [E]
    int2*  recs_mid = recs + E;                              // [E]
    unsigned* bcnt  = (unsigned*)(recs_mid + E);             // [NBUK*CB]
    unsigned* btotal= bcnt + (size_t)NBUK * CB;              // [NBUK]
    unsigned* bbase = btotal + NBUK;                         // [NBUK+1]
    float* dinv     = (float*)(bbase + NBUK + 1);            // [N]
    int*   rowptr   = (int*)(dinv + N);                      // [N+1]
    float* stats    = (float*)(rowptr + N + 1);              // 512
    float* prm      = stats + 512;                           // 256
    float* partial  = prm + 256;                             // [GB*256]

    // Wt staged in d_out (scratch until final bn_relu overwrites)
    short* Wt0 = (short*)d_out;            // [128][256] bf16
    short* Wt1 = Wt0 + 256 * 128;          // [128][128] bf16

    const int gemm_blocks = (N + 31) / 32;

    // ---- prep + atomic-free CSR build (phase A fused with gemm0) ----
    hipMemsetAsync(stats, 0, 512 * sizeof(float), stream);
    k_prep_w2<<<192, 256, 0, stream>>>(W0, W1, Wt0, Wt1);
    k_phaseA<<<CB + gemm_blocks, 256, 0, stream>>>(ei, E, CB, CHUNK, NBUK, bcnt,
                                                   x, Wt0, hbf, N);
    k_phaseB<<<NBUK, 256, 0, stream>>>(bcnt, btotal, CB, NBUK);
    k_bsum<<<1, 256, 0, stream>>>(btotal, bbase, NBUK, E);
    k_phaseC<<<CB, 256, 0, stream>>>(ei, ew, E, CB, CHUNK, NBUK, bcnt, bbase, recs_mid);
    k_phaseD<<<NBUK, 256, 0, stream>>>(recs_mid, bbase, dinv, rowptr, recs, N, E);
    k_phaseE<<<(E + 255) / 256, 256, 0, stream>>>(recs, dinv, E);

    // ---- layer 0 ----
    k_gather_stats<<<GB, 256, 0, stream>>>(hbf, agg, rowptr, recs, dinv, b0,
                                           partial, N, GB * 4);
    k_stats_red<<<64, 256, 0, stream>>>(partial, stats, GB);
    k_bn_params<<<1, 128, 0, stream>>>(stats, g0, be0, prm, N);

    // ---- layer 1 (BN0+ReLU fused into GEMM A-load) ----
    k_gemm1<<<gemm_blocks, 256, 0, stream>>>(agg, Wt1, prm, hbf, N);
    k_gather_stats<<<GB, 256, 0, stream>>>(hbf, agg, rowptr, recs, dinv, b1,
                                           partial, N, GB * 4);
    k_stats_red<<<64, 256, 0, stream>>>(partial, stats + 256, GB);
    k_bn_params<<<1, 128, 0, stream>>>(stats + 256, g1, be1, prm, N);
    k_bn_relu<<<2048, 256, 0, stream>>>(agg, out, prm, N);
}

// Round 7
// 393.971 us; speedup vs baseline: 7.5679x; 1.0361x over previous
//
#include <hip/hip_runtime.h>
#include <stdint.h>

#define FIN 256
#define FHID 128
#define BN_EPS 1e-3f

typedef short bf16x8 __attribute__((ext_vector_type(8)));
typedef float f32x4 __attribute__((ext_vector_type(4)));

__device__ inline short f2bf(float f) {
    unsigned u = __float_as_uint(f);
    unsigned r = (u + 0x7FFFu + ((u >> 16) & 1u)) >> 16;   // RNE
    return (short)r;
}
__device__ inline float bflo(unsigned v) { return __uint_as_float(v << 16); }
__device__ inline float bfhi(unsigned v) { return __uint_as_float(v & 0xFFFF0000u); }

#define DEG_SCALE 131072.0f          // 2^17 fixed point
#define DEG_INV   (1.0f / 131072.0f)

// ---------------- W0,W1 -> bf16 transposed [n][k] ----------------
__global__ __launch_bounds__(256) void k_prep_w2(const float* __restrict__ W0,
                                                 const float* __restrict__ W1,
                                                 short* __restrict__ Wt0,
                                                 short* __restrict__ Wt1) {
    int idx = blockIdx.x * 256 + threadIdx.x;
    if (idx < 32768) {            // W0: [256][128] -> Wt0 [128][256]
        int n = idx >> 8, k = idx & 255;
        Wt0[idx] = f2bf(W0[k * 128 + n]);
    } else {
        int j = idx - 32768;      // W1: [128][128] -> Wt1 [128][128]
        if (j < 16384) {
            int n = j >> 7, k = j & 127;
            Wt1[j] = f2bf(W1[k * 128 + n]);
        }
    }
}

// ---------------- MFMA GEMM core (chunked A prefetch for ILP) ----------------
template <int K, bool INF32, bool BN>
__device__ __forceinline__ void gemm_core(int bid, const void* __restrict__ Xv,
                                          const short* __restrict__ Wt,
                                          const float* __restrict__ prm,
                                          short* __restrict__ H, int nrows) {
    constexpr int KS = K / 32;
    const int lane = threadIdx.x & 63;
    const int w = threadIdx.x >> 6;
    const int r0 = bid * 32;
    const int n0 = w * 32;
    const int l15 = lane & 15;
    const int lk = (lane >> 4) * 8;

    bf16x8 b[KS][2];
#pragma unroll
    for (int ks = 0; ks < KS; ks++)
#pragma unroll
        for (int nf = 0; nf < 2; nf++)
            b[ks][nf] = *reinterpret_cast<const bf16x8*>(
                Wt + (size_t)(n0 + nf * 16 + l15) * K + ks * 32 + lk);

    f32x4 acc[2][2];
#pragma unroll
    for (int mf = 0; mf < 2; mf++)
#pragma unroll
        for (int nf = 0; nf < 2; nf++)
#pragma unroll
            for (int r = 0; r < 4; r++) acc[mf][nf][r] = 0.0f;

    if (INF32) {
#pragma unroll
        for (int mf = 0; mf < 2; mf++) {
            int row = r0 + mf * 16 + l15;
            if (row >= nrows) row = nrows - 1;
            const float* rowp = (const float*)Xv + (size_t)row * K + lk;
#pragma unroll
            for (int ch = 0; ch < KS / 4; ch++) {
                float4 u[8];
#pragma unroll
                for (int c = 0; c < 4; c++) {
                    u[2 * c]     = *reinterpret_cast<const float4*>(rowp + (ch * 4 + c) * 32);
                    u[2 * c + 1] = *reinterpret_cast<const float4*>(rowp + (ch * 4 + c) * 32 + 4);
                }
#pragma unroll
                for (int c = 0; c < 4; c++) {
                    const int ks = ch * 4 + c;
                    float4 u0 = u[2 * c], u1 = u[2 * c + 1];
                    if (BN) {
                        const int kb = ks * 32 + lk;
                        const float4 sc0 = *reinterpret_cast<const float4*>(prm + kb);
                        const float4 sc1 = *reinterpret_cast<const float4*>(prm + kb + 4);
                        const float4 sh0 = *reinterpret_cast<const float4*>(prm + 128 + kb);
                        const float4 sh1 = *reinterpret_cast<const float4*>(prm + 128 + kb + 4);
                        u0.x = fmaxf(u0.x * sc0.x + sh0.x, 0.f);
                        u0.y = fmaxf(u0.y * sc0.y + sh0.y, 0.f);
                        u0.z = fmaxf(u0.z * sc0.z + sh0.z, 0.f);
                        u0.w = fmaxf(u0.w * sc0.w + sh0.w, 0.f);
                        u1.x = fmaxf(u1.x * sc1.x + sh1.x, 0.f);
                        u1.y = fmaxf(u1.y * sc1.y + sh1.y, 0.f);
                        u1.z = fmaxf(u1.z * sc1.z + sh1.z, 0.f);
                        u1.w = fmaxf(u1.w * sc1.w + sh1.w, 0.f);
                    }
                    bf16x8 a;
                    a[0] = f2bf(u0.x); a[1] = f2bf(u0.y); a[2] = f2bf(u0.z); a[3] = f2bf(u0.w);
                    a[4] = f2bf(u1.x); a[5] = f2bf(u1.y); a[6] = f2bf(u1.z); a[7] = f2bf(u1.w);
                    acc[mf][0] = __builtin_amdgcn_mfma_f32_16x16x32_bf16(a, b[ks][0], acc[mf][0], 0, 0, 0);
                    acc[mf][1] = __builtin_amdgcn_mfma_f32_16x16x32_bf16(a, b[ks][1], acc[mf][1], 0, 0, 0);
                }
            }
        }
    } else {
#pragma unroll
        for (int ks = 0; ks < KS; ks++) {
            bf16x8 a[2];
#pragma unroll
            for (int mf = 0; mf < 2; mf++) {
                int row = r0 + mf * 16 + l15;
                if (row >= nrows) row = nrows - 1;
                a[mf] = *reinterpret_cast<const bf16x8*>(
                    (const short*)Xv + (size_t)row * K + ks * 32 + lk);
            }
#pragma unroll
            for (int mf = 0; mf < 2; mf++)
#pragma unroll
                for (int nf = 0; nf < 2; nf++)
                    acc[mf][nf] = __builtin_amdgcn_mfma_f32_16x16x32_bf16(
                        a[mf], b[ks][nf], acc[mf][nf], 0, 0, 0);
        }
    }

#pragma unroll
    for (int mf = 0; mf < 2; mf++) {
        const int rbase = r0 + mf * 16 + (lane >> 4) * 4;
#pragma unroll
        for (int r = 0; r < 4; r++) {
            const int row = rbase + r;
            if (row < nrows) {
#pragma unroll
                for (int nf = 0; nf < 2; nf++)
                    H[(size_t)row * 128 + n0 + nf * 16 + l15] = f2bf(acc[mf][nf][r]);
            }
        }
    }
}

// ---------------- phase A: per-block LDS bucket histogram || gemm0 ----------
__global__ __launch_bounds__(256) void k_phaseA(const int* __restrict__ ei, int E,
                                                int CB, int CHUNK, int nbuk,
                                                unsigned* __restrict__ bcnt,
                                                const float* __restrict__ x,
                                                const short* __restrict__ Wt0,
                                                short* __restrict__ H, int nrows) {
    __shared__ unsigned hist[1024];
    if ((int)blockIdx.x < CB) {
        for (int i = threadIdx.x; i < nbuk; i += 256) hist[i] = 0;
        __syncthreads();
        const int e0 = blockIdx.x * CHUNK;
        const int e1 = min(e0 + CHUNK, E);
        for (int e = e0 + threadIdx.x; e < e1; e += 256)
            atomicAdd(&hist[ei[E + e] >> 7], 1u);
        __syncthreads();
        for (int k = threadIdx.x; k < nbuk; k += 256)
            bcnt[(size_t)blockIdx.x * nbuk + k] = hist[k];   // coalesced
    } else {
        gemm_core<FIN, true, false>(blockIdx.x - CB, x, Wt0, nullptr, H, nrows);
    }
}

// ---------------- phase B: per-bucket scan of block counts (in-place) -------
__global__ __launch_bounds__(256) void k_phaseB(unsigned* __restrict__ bcnt,
                                                unsigned* __restrict__ btotal,
                                                int CB, int nbuk) {
    __shared__ unsigned lds[256];
    const int k = blockIdx.x;   // bucket
    const int t = threadIdx.x;  // block index (CB<=256)
    unsigned v = (t < CB) ? bcnt[(size_t)t * nbuk + k] : 0;
    lds[t] = v;
    __syncthreads();
    for (int off = 1; off < 256; off <<= 1) {
        unsigned add = (t >= off) ? lds[t - off] : 0;
        __syncthreads();
        lds[t] += add;
        __syncthreads();
    }
    if (t < CB) bcnt[(size_t)t * nbuk + k] = lds[t] - v;   // exclusive
    if (t == 255) btotal[k] = lds[255];
}

// ---------------- bucket base scan (single block) ----------------
__global__ __launch_bounds__(256) void k_bsum(const unsigned* __restrict__ btotal,
                                              unsigned* __restrict__ bbase,
                                              int nbuk, int E) {
    __shared__ unsigned lds[256];
    const int t = threadIdx.x;
    unsigned v[4];
    unsigned s = 0;
#pragma unroll
    for (int i = 0; i < 4; i++) {
        int j = t * 4 + i;
        v[i] = (j < nbuk) ? btotal[j] : 0;
        s += v[i];
    }
    lds[t] = s;
    __syncthreads();
    for (int off = 1; off < 256; off <<= 1) {
        unsigned add = (t >= off) ? lds[t - off] : 0;
        __syncthreads();
        lds[t] += add;
        __syncthreads();
    }
    unsigned run = lds[t] - s;
#pragma unroll
    for (int i = 0; i < 4; i++) {
        int j = t * 4 + i;
        if (j < nbuk) bbase[j] = run;
        run += v[i];
    }
    if (t == 255) bbase[nbuk] = (unsigned)E;
}

// ---------------- phase C: bucket-scatter edges (LDS cursors) ----------------
__global__ __launch_bounds__(256) void k_phaseC(const int* __restrict__ ei,
                                                const float* __restrict__ ew,
                                                int E, int CB, int CHUNK, int nbuk,
                                                const unsigned* __restrict__ bcur,
                                                const unsigned* __restrict__ bbase,
                                                int2* __restrict__ recs_mid) {
    __shared__ unsigned curs[1024];
    const int b = blockIdx.x;
    for (int k = threadIdx.x; k < nbuk; k += 256)
        curs[k] = bbase[k] + bcur[(size_t)b * nbuk + k];
    __syncthreads();
    const int e0 = b * CHUNK;
    const int e1 = min(e0 + CHUNK, E);
    for (int e = e0 + threadIdx.x; e < e1; e += 256) {
        int src = ei[e];
        int dst = ei[E + e];
        unsigned pos = atomicAdd(&curs[dst >> 7], 1u);
        recs_mid[pos] = make_int2(src | ((dst & 127) << 17), __float_as_int(ew[e]));
    }
}

// ---------------- phase D: per-bucket dst sort, dinv, rowptr, recs ----------
__global__ __launch_bounds__(256) void k_phaseD(const int2* __restrict__ recs_mid,
                                                const unsigned* __restrict__ bbase,
                                                float* __restrict__ dinv,
                                                int* __restrict__ rowptr,
                                                int2* __restrict__ recs,
                                                int n, int E) {
    __shared__ unsigned cnt[128], wsum[128], rank[128], sc[128], base[128];
    __shared__ float dloc[128];
    const int k = blockIdx.x;
    const int t = threadIdx.x;
    if (t < 128) { cnt[t] = 0; wsum[t] = 0; rank[t] = 0; }
    __syncthreads();
    const unsigned s0 = bbase[k], s1 = bbase[k + 1];
    for (unsigned i = s0 + t; i < s1; i += 256) {
        int2 r = recs_mid[i];
        int dl = (r.x >> 17) & 127;
        atomicAdd(&cnt[dl], 1u);
        atomicAdd(&wsum[dl], (unsigned)(__int_as_float(r.y) * DEG_SCALE));
    }
    __syncthreads();
    if (t < 128) sc[t] = cnt[t];
    __syncthreads();
    for (int off = 1; off < 128; off <<= 1) {
        unsigned add = (t < 128 && t >= off) ? sc[t - off] : 0;
        __syncthreads();
        if (t < 128) sc[t] += add;
        __syncthreads();
    }
    if (t < 128) {
        unsigned excl = sc[t] - cnt[t];
        base[t] = s0 + excl;
        int dst = k * 128 + t;
        if (dst < n) {
            float deg = (float)wsum[t] * DEG_INV + 1.0f;
            float dv = rsqrtf(deg);
            dloc[t] = dv;
            dinv[dst] = dv;
            rowptr[dst] = (int)(s0 + excl);
        }
    }
    if (k == 0 && t == 0) rowptr[n] = E;
    __syncthreads();
    for (unsigned i = s0 + t; i < s1; i += 256) {
        int2 r = recs_mid[i];
        int dl = (r.x >> 17) & 127;
        unsigned rr = atomicAdd(&rank[dl], 1u);
        float w2 = __int_as_float(r.y) * dloc[dl];     // ew * dinv[dst]
        recs[base[dl] + rr] = make_int2(r.x & 0x1FFFF, __float_as_int(w2));
    }
}

// ---------------- phase E: fold dinv[src] into rec weight ----------------
__global__ __launch_bounds__(256) void k_phaseE(int2* __restrict__ recs,
                                                const float* __restrict__ dinv, int E) {
    int i = blockIdx.x * 256 + threadIdx.x;
    if (i < E) {
        int2 r = recs[i];
        float w = __int_as_float(r.y) * dinv[r.x];
        recs[i] = make_int2(r.x, __float_as_int(w));
    }
}

// ---------------- standalone GEMM layer 1 (BN0+ReLU fused) ----------------
__global__ __launch_bounds__(256) void k_gemm1(const float* __restrict__ X,
                                               const short* __restrict__ Wt,
                                               const float* __restrict__ prm,
                                               short* __restrict__ H, int nrows) {
    gemm_core<FHID, true, true>(blockIdx.x, X, Wt, prm, H, nrows);
}

// ---------------- gather + fused stats: 2 edges/wave-instr, 8 rows in flight -
__global__ __launch_bounds__(256) void k_gather_stats(const short* __restrict__ h,
                                                      float* __restrict__ agg,
                                                      const int* __restrict__ rowptr,
                                                      const int2* __restrict__ recs,
                                                      const float* __restrict__ dinv,
                                                      const float* __restrict__ bias,
                                                      float* __restrict__ partial,
                                                      int n, int nwaves) {
    __shared__ float lsum[4][128], lsq[4][128];
    const int w = threadIdx.x >> 6;
    const int lane = threadIdx.x & 63;
    const int half = lane >> 5;          // which edge of the pair
    const int q = lane & 31;             // 4-feature slot within row
    const float4 bv = *reinterpret_cast<const float4*>(bias + q * 4);
    float s0 = 0.f, s1 = 0.f, s2 = 0.f, s3 = 0.f;
    float q0 = 0.f, q1 = 0.f, q2 = 0.f, q3 = 0.f;

    for (int node = blockIdx.x * 4 + w; node < n; node += nwaves) {
        float a0 = 0.f, a1 = 0.f, a2 = 0.f, a3 = 0.f;
        int e = rowptr[node];
        const int end = rowptr[node + 1];
        for (; e + 8 <= end; e += 8) {
            const int2 r0 = recs[e + half];
            const int2 r1 = recs[e + half + 2];
            const int2 r2 = recs[e + half + 4];
            const int2 r3 = recs[e + half + 6];
            const uint2 v0 = *reinterpret_cast<const uint2*>(h + (size_t)r0.x * 128 + q * 4);
            const uint2 v1 = *reinterpret_cast<const uint2*>(h + (size_t)r1.x * 128 + q * 4);
            const uint2 v2 = *reinterpret_cast<const uint2*>(h + (size_t)r2.x * 128 + q * 4);
            const uint2 v3 = *reinterpret_cast<const uint2*>(h + (size_t)r3.x * 128 + q * 4);
            const float w0 = __int_as_float(r0.y);
            const float w1 = __int_as_float(r1.y);
            const float w2 = __int_as_float(r2.y);
            const float w3 = __int_as_float(r3.y);
            a0 += bflo(v0.x) * w0; a1 += bfhi(v0.x) * w0; a2 += bflo(v0.y) * w0; a3 += bfhi(v0.y) * w0;
            a0 += bflo(v1.x) * w1; a1 += bfhi(v1.x) * w1; a2 += bflo(v1.y) * w1; a3 += bfhi(v1.y) * w1;
            a0 += bflo(v2.x) * w2; a1 += bfhi(v2.x) * w2; a2 += bflo(v2.y) * w2; a3 += bfhi(v2.y) * w2;
            a0 += bflo(v3.x) * w3; a1 += bfhi(v3.x) * w3; a2 += bflo(v3.y) * w3; a3 += bfhi(v3.y) * w3;
        }
        for (; e + half < end; e += 2) {
            const int2 r = recs[e + half];
            const uint2 v = *reinterpret_cast<const uint2*>(h + (size_t)r.x * 128 + q * 4);
            const float w0 = __int_as_float(r.y);
            a0 += bflo(v.x) * w0; a1 += bfhi(v.x) * w0; a2 += bflo(v.y) * w0; a3 += bfhi(v.y) * w0;
        }
        // cross-half reduction (sum the two edge streams)
        a0 += __shfl_xor(a0, 32);
        a1 += __shfl_xor(a1, 32);
        a2 += __shfl_xor(a2, 32);
        a3 += __shfl_xor(a3, 32);
        if (half == 0) {
            const float di = dinv[node];
            const float sl = di * di;
            const uint2 hv = *reinterpret_cast<const uint2*>(h + (size_t)node * 128 + q * 4);
            const float o0 = a0 + bflo(hv.x) * sl + bv.x;
            const float o1 = a1 + bfhi(hv.x) * sl + bv.y;
            const float o2 = a2 + bflo(hv.y) * sl + bv.z;
            const float o3 = a3 + bfhi(hv.y) * sl + bv.w;
            *reinterpret_cast<float4*>(agg + (size_t)node * 128 + q * 4) =
                make_float4(o0, o1, o2, o3);
            s0 += o0; q0 += o0 * o0;
            s1 += o1; q1 += o1 * o1;
            s2 += o2; q2 += o2 * o2;
            s3 += o3; q3 += o3 * o3;
        }
    }

    if (half == 0) {
        *reinterpret_cast<float4*>(&lsum[w][q * 4]) = make_float4(s0, s1, s2, s3);
        *reinterpret_cast<float4*>(&lsq[w][q * 4]) = make_float4(q0, q1, q2, q3);
    }
    __syncthreads();
    const int t = threadIdx.x;
    if (t < 128) {
        float ps = lsum[0][t] + lsum[1][t] + lsum[2][t] + lsum[3][t];
        float pq = lsq[0][t] + lsq[1][t] + lsq[2][t] + lsq[3][t];
        partial[(size_t)blockIdx.x * 256 + t] = ps;
        partial[(size_t)blockIdx.x * 256 + 128 + t] = pq;
    }
}

// ---------------- reduce partials -> stats ----------------
__global__ __launch_bounds__(256) void k_stats_red(const float* __restrict__ partial,
                                                   float* __restrict__ stats, int nblk) {
    const int gid = blockIdx.x * 256 + threadIdx.x;   // grid = 64 blocks
    const int slot = gid & 255;
    const int chunk = gid >> 8;
    const int per = nblk >> 6;
    float v = 0.f;
    for (int p = chunk * per; p < (chunk + 1) * per; p++)
        v += partial[(size_t)p * 256 + slot];
    atomicAdd(&stats[slot], v);
}

__global__ void k_bn_params(const float* __restrict__ stats,
                            const float* __restrict__ g,
                            const float* __restrict__ beta,
                            float* __restrict__ prm, int n) {
    int f = threadIdx.x;
    float inv_n = 1.0f / (float)n;
    float mu = stats[f] * inv_n;
    float var = stats[128 + f] * inv_n - mu * mu;
    float sc = rsqrtf(var + BN_EPS) * g[f];
    prm[f] = sc;
    prm[128 + f] = beta[f] - mu * sc;
}

// ---------------- final BN apply + ReLU (f32 out) ----------------
__global__ __launch_bounds__(256) void k_bn_relu(const float* __restrict__ x,
                                                 float* __restrict__ y,
                                                 const float* __restrict__ prm, int n) {
    int idx = blockIdx.x * blockDim.x + threadIdx.x;
    const int total = n * 32;
    for (; idx < total; idx += gridDim.x * blockDim.x) {
        int node = idx >> 5;
        int c4 = (idx & 31) * 4;
        const float4 xv = *reinterpret_cast<const float4*>(x + (size_t)node * 128 + c4);
        const float4 sc = *reinterpret_cast<const float4*>(prm + c4);
        const float4 sh = *reinterpret_cast<const float4*>(prm + 128 + c4);
        float4 o;
        o.x = fmaxf(xv.x * sc.x + sh.x, 0.f);
        o.y = fmaxf(xv.y * sc.y + sh.y, 0.f);
        o.z = fmaxf(xv.z * sc.z + sh.z, 0.f);
        o.w = fmaxf(xv.w * sc.w + sh.w, 0.f);
        *reinterpret_cast<float4*>(y + (size_t)node * 128 + c4) = o;
    }
}

extern "C" void kernel_launch(void* const* d_in, const int* in_sizes, int n_in,
                              void* d_out, int out_size, void* d_ws, size_t ws_size,
                              hipStream_t stream) {
    const float* x   = (const float*)d_in[0];
    const int*   ei  = (const int*)d_in[1];
    const float* ew  = (const float*)d_in[2];
    const float* W0  = (const float*)d_in[3];
    const float* b0  = (const float*)d_in[4];
    const float* g0  = (const float*)d_in[5];
    const float* be0 = (const float*)d_in[6];
    const float* W1  = (const float*)d_in[7];
    const float* b1  = (const float*)d_in[8];
    const float* g1  = (const float*)d_in[9];
    const float* be1 = (const float*)d_in[10];
    float* out = (float*)d_out;

    const int N = in_sizes[0] / FIN;          // 100000
    const int E = in_sizes[2];                // 1600000
    const int NBUK = (N + 127) >> 7;          // 782
    const int CB = 256;                       // edge chunks (<= 256 for phaseB)
    const int CHUNK = (E + CB - 1) / CB;      // 6250
    const int GB = 2048;                      // gather grid

    // workspace layout
    float* agg      = (float*)d_ws;                          // [N,128] f32
    short* hbf      = (short*)(agg + (size_t)N * 128);       // [N,128] bf16
    int2*  recs     = (int2*)(hbf + (size_t)N * 128);        // [E]
    int2*  recs_mid = recs + E;                              // [E]
    unsigned* bcnt  = (unsigned*)(recs_mid + E);             // [CB*NBUK]
    unsigned* btotal= bcnt + (size_t)CB * NBUK;              // [NBUK]
    unsigned* bbase = btotal + NBUK;                         // [NBUK+1]
    float* dinv     = (float*)(bbase + NBUK + 1);            // [N]
    int*   rowptr   = (int*)(dinv + N);                      // [N+1]
    float* stats    = (float*)(rowptr + N + 1);              // 512
    float* prm      = stats + 512;                           // 256
    float* partial  = prm + 256;                             // [GB*256]

    // Wt staged in d_out (scratch until final bn_relu overwrites)
    short* Wt0 = (short*)d_out;            // [128][256] bf16
    short* Wt1 = Wt0 + 256 * 128;          // [128][128] bf16

    const int gemm_blocks = (N + 31) / 32;

    // ---- prep + atomic-free CSR build (phase A fused with gemm0) ----
    hipMemsetAsync(stats, 0, 512 * sizeof(float), stream);
    k_prep_w2<<<192, 256, 0, stream>>>(W0, W1, Wt0, Wt1);
    k_phaseA<<<CB + gemm_blocks, 256, 0, stream>>>(ei, E, CB, CHUNK, NBUK, bcnt,
                                                   x, Wt0, hbf, N);
    k_phaseB<<<NBUK, 256, 0, stream>>>(bcnt, btotal, CB, NBUK);
    k_bsum<<<1, 256, 0, stream>>>(btotal, bbase, NBUK, E);
    k_phaseC<<<CB, 256, 0, stream>>>(ei, ew, E, CB, CHUNK, NBUK, bcnt, bbase, recs_mid);
    k_phaseD<<<NBUK, 256, 0, stream>>>(recs_mid, bbase, dinv, rowptr, recs, N, E);
    k_phaseE<<<(E + 255) / 256, 256, 0, stream>>>(recs, dinv, E);

    // ---- layer 0 ----
    k_gather_stats<<<GB, 256, 0, stream>>>(hbf, agg, rowptr, recs, dinv, b0,
                                           partial, N, GB * 4);
    k_stats_red<<<64, 256, 0, stream>>>(partial, stats, GB);
    k_bn_params<<<1, 128, 0, stream>>>(stats, g0, be0, prm, N);

    // ---- layer 1 (BN0+ReLU fused into GEMM A-load) ----
    k_gemm1<<<gemm_blocks, 256, 0, stream>>>(agg, Wt1, prm, hbf, N);
    k_gather_stats<<<GB, 256, 0, stream>>>(hbf, agg, rowptr, recs, dinv, b1,
                                           partial, N, GB * 4);
    k_stats_red<<<64, 256, 0, stream>>>(partial, stats + 256, GB);
    k_bn_params<<<1, 128, 0, stream>>>(stats + 256, g1, be1, prm, N);
    k_bn_relu<<<2048, 256, 0, stream>>>(agg, out, prm, N);
}